// Round 1
// baseline (654.717 us; speedup 1.0000x reference)
//
#include <hip/hip_runtime.h>
#include <hip/hip_bf16.h>

#define N_NODES 100000
#define N_TYPES 10
#define N_EDGES 3200000
#define HIDDEN 256
#define EMBED 128
#define N_PAIRS 100000

typedef _Float16 half2v __attribute__((ext_vector_type(2)));
typedef _Float16 half4v __attribute__((ext_vector_type(4)));
typedef _Float16 half8v __attribute__((ext_vector_type(8)));
typedef float floatx4 __attribute__((ext_vector_type(4)));

#define GLOBAL_AS __attribute__((address_space(1)))
#define LDS_AS __attribute__((address_space(3)))

static __device__ __forceinline__ void async_copy16(const void* g, void* lds) {
    __builtin_amdgcn_global_load_lds((const GLOBAL_AS unsigned int*)g,
                                     (LDS_AS unsigned int*)(void*)lds, 16, 0, 0);
}

// ---------------------------------------------------------------------------
// row_ptr from sorted rows (binary search, no atomics)
// ---------------------------------------------------------------------------
__global__ void build_rowptr_k(const int* __restrict__ rows, int* __restrict__ rp,
                               int n_nodes, int n_edges) {
    int n = blockIdx.x * blockDim.x + threadIdx.x;
    if (n > n_nodes) return;
    int lo = 0, hi = n_edges;
    while (lo < hi) {
        int mid = (lo + hi) >> 1;
        if (rows[mid] < n) lo = mid + 1; else hi = mid;
    }
    rp[n] = lo;
}

// ---------------------------------------------------------------------------
// x16[n][f] = fp16(node_emb[n][f] + type_emb[type[n]][f])
// ---------------------------------------------------------------------------
__global__ void build_x16_k(const float* __restrict__ node_emb,
                            const float* __restrict__ type_emb,
                            const int* __restrict__ ntype,
                            _Float16* __restrict__ x16) {
    int idx = blockIdx.x * blockDim.x + threadIdx.x;
    int n  = idx >> 6;
    if (n >= N_NODES) return;
    int f4 = (idx & 63) * 4;
    int t = ntype[n];
    float4 a = *(const float4*)&node_emb[(size_t)n * HIDDEN + f4];
    float4 b = *(const float4*)&type_emb[(size_t)t * HIDDEN + f4];
    half4v o;
    o.x = (_Float16)(a.x + b.x);
    o.y = (_Float16)(a.y + b.y);
    o.z = (_Float16)(a.z + b.z);
    o.w = (_Float16)(a.w + b.w);
    *(half4v*)&x16[(size_t)n * HIDDEN + f4] = o;
}

// ---------------------------------------------------------------------------
// Wt[n][k] = fp16(W[k][n])  for K=256 weights (W1, W2)
// ---------------------------------------------------------------------------
__global__ void transpose_w_k(const float* __restrict__ W, _Float16* __restrict__ Wt,
                              int K, int N) {
    int idx = blockIdx.x * blockDim.x + threadIdx.x;   // idx = n*256 + k
    if (idx >= K * N) return;
    int k = idx & 255;
    int n = idx >> 8;
    Wt[idx] = (_Float16)W[(size_t)k * N + n];
}

// Wp1 [384,128] -> Wp1t [128][384] fp16
__global__ void transpose_wp1_k(const float* __restrict__ W, _Float16* __restrict__ Wt) {
    int k = threadIdx.x;   // 0..383
    int n = blockIdx.x;    // 0..127
    Wt[n * 384 + k] = (_Float16)W[(size_t)k * EMBED + n];
}

// ---------------------------------------------------------------------------
// spmm1: s1[n][0:256] fp16 = sum_e val[e] * x16[cols[e]][:]
// one wave/node; 16B/lane gathers, 32 lanes/row -> 2 edges per instruction;
// 5-deep unroll = 10 edges / 5KB in flight per wave; shfl_xor(32) reduce.
// ---------------------------------------------------------------------------
__global__ __launch_bounds__(256, 8) void spmm1_k(
        const int* __restrict__ rp, const int* __restrict__ cols,
        const float* __restrict__ vals,
        const _Float16* __restrict__ x16, _Float16* __restrict__ s1) {
    int wave = threadIdx.x >> 6, lane = threadIdx.x & 63;
    int n = blockIdx.x * 4 + wave;
    int e0 = rp[n], e1 = rp[n + 1];
    int g  = lane >> 5;          // edge slot 0/1
    int fo = (lane & 31) * 8;    // 8 feats (16B) per lane
    float acc[8];
#pragma unroll
    for (int j = 0; j < 8; ++j) acc[j] = 0.f;

    int e = e0;
    for (; e + 10 <= e1; e += 10) {
        int c[5]; float v[5];
#pragma unroll
        for (int i = 0; i < 5; ++i) {
            c[i] = cols[e + 2 * i + g];
            v[i] = vals[e + 2 * i + g];
        }
        half8v h[5];
#pragma unroll
        for (int i = 0; i < 5; ++i)
            h[i] = *(const half8v*)&x16[(size_t)c[i] * HIDDEN + fo];
#pragma unroll
        for (int i = 0; i < 5; ++i)
#pragma unroll
            for (int j = 0; j < 8; ++j)
                acc[j] += v[i] * (float)h[i][j];
    }
    for (; e < e1; e += 2) {
        int idx = e + g;
        bool ok = idx < e1;
        int c0 = cols[ok ? idx : e];
        float v0 = ok ? vals[idx] : 0.f;
        half8v h0 = *(const half8v*)&x16[(size_t)c0 * HIDDEN + fo];
#pragma unroll
        for (int j = 0; j < 8; ++j)
            acc[j] += v0 * (float)h0[j];
    }
#pragma unroll
    for (int j = 0; j < 8; ++j)
        acc[j] += __shfl_xor(acc[j], 32, 64);
    if (lane < 32) {
        half8v o;
#pragma unroll
        for (int j = 0; j < 8; ++j) o[j] = (_Float16)acc[j];
        *(half8v*)&s1[(size_t)n * HIDDEN + fo] = o;
    }
}

// ---------------------------------------------------------------------------
// spmm2: z16[n][0:128] fp16 = sum_e val[e] * g16[cols[e]][:] + b2
// one wave/node; 16B/lane gathers, 16 lanes/row -> 4 edges per instruction;
// 4-deep unroll = 16 edges / 4KB in flight per wave; shfl_xor(16,32) reduce.
// ---------------------------------------------------------------------------
__global__ __launch_bounds__(256, 8) void spmm2_k(
        const int* __restrict__ rp, const int* __restrict__ cols,
        const float* __restrict__ vals,
        const _Float16* __restrict__ g16,
        const float* __restrict__ b2, _Float16* __restrict__ z16) {
    int wave = threadIdx.x >> 6, lane = threadIdx.x & 63;
    int n = blockIdx.x * 4 + wave;
    int e0 = rp[n], e1 = rp[n + 1];
    int q  = lane >> 4;          // edge slot 0..3
    int fo = (lane & 15) * 8;    // 8 feats (16B) per lane
    float acc[8];
#pragma unroll
    for (int j = 0; j < 8; ++j) acc[j] = 0.f;

    int e = e0;
    for (; e + 16 <= e1; e += 16) {
        int c[4]; float v[4];
#pragma unroll
        for (int i = 0; i < 4; ++i) {
            c[i] = cols[e + 4 * i + q];
            v[i] = vals[e + 4 * i + q];
        }
        half8v h[4];
#pragma unroll
        for (int i = 0; i < 4; ++i)
            h[i] = *(const half8v*)&g16[(size_t)c[i] * EMBED + fo];
#pragma unroll
        for (int i = 0; i < 4; ++i)
#pragma unroll
            for (int j = 0; j < 8; ++j)
                acc[j] += v[i] * (float)h[i][j];
    }
    for (; e < e1; e += 4) {
        int idx = e + q;
        bool ok = idx < e1;
        int c0 = cols[ok ? idx : e];
        float v0 = ok ? vals[idx] : 0.f;
        half8v h0 = *(const half8v*)&g16[(size_t)c0 * EMBED + fo];
#pragma unroll
        for (int j = 0; j < 8; ++j)
            acc[j] += v0 * (float)h0[j];
    }
#pragma unroll
    for (int j = 0; j < 8; ++j) {
        acc[j] += __shfl_xor(acc[j], 16, 64);
        acc[j] += __shfl_xor(acc[j], 32, 64);
    }
    if (lane < 16) {
        half8v o;
#pragma unroll
        for (int j = 0; j < 8; ++j) o[j] = (_Float16)(acc[j] + b2[fo + j]);
        *(half8v*)&z16[(size_t)n * EMBED + fo] = o;
    }
}

// ---------------------------------------------------------------------------
// fp16 MFMA GEMM: C16 = [relu](A @ Bt^T + bias), A [M,256], Bt [N,256]
// 128x128 tile, BK=32, 256 thr, global_load_lds width-16 staging
// ---------------------------------------------------------------------------
template <bool RELU, bool BIAS>
__global__ void gemm16_k(const _Float16* __restrict__ A,
                         const _Float16* __restrict__ Bt,
                         const float* __restrict__ bias,
                         _Float16* __restrict__ C,
                         int M, int N) {
    const int K = 256;
    __shared__ _Float16 As[128 * 32];
    __shared__ _Float16 Bs[128 * 32];

    int t = threadIdx.x;
    int lane = t & 63;
    int wave = t >> 6;
    int quad = lane >> 4;
    int m16 = lane & 15;
    int wr = wave >> 1, wc = wave & 1;
    int m0 = blockIdx.x * 128;
    int n0 = blockIdx.y * 128;

    int srow = t >> 2;
    int skoff = (t & 3) * 8;

    floatx4 acc[4][4];
#pragma unroll
    for (int i = 0; i < 4; ++i)
#pragma unroll
        for (int j = 0; j < 4; ++j)
            acc[i][j] = (floatx4)0.f;

    for (int k0 = 0; k0 < K; k0 += 32) {
        int ra0 = m0 + srow;       if (ra0 >= M) ra0 = M - 1;
        int ra1 = m0 + srow + 64;  if (ra1 >= M) ra1 = M - 1;
        async_copy16(&A[(size_t)ra0 * K + k0 + skoff], &As[srow * 32 + skoff]);
        async_copy16(&A[(size_t)ra1 * K + k0 + skoff], &As[(srow + 64) * 32 + skoff]);
        async_copy16(&Bt[(size_t)(n0 + srow) * K + k0 + skoff], &Bs[srow * 32 + skoff]);
        async_copy16(&Bt[(size_t)(n0 + srow + 64) * K + k0 + skoff], &Bs[(srow + 64) * 32 + skoff]);
        __syncthreads();

        half8v aF[4], bF[4];
#pragma unroll
        for (int i = 0; i < 4; ++i)
            aF[i] = *(const half8v*)&As[(wr * 64 + i * 16 + m16) * 32 + quad * 8];
#pragma unroll
        for (int j = 0; j < 4; ++j)
            bF[j] = *(const half8v*)&Bs[(wc * 64 + j * 16 + m16) * 32 + quad * 8];
#pragma unroll
        for (int i = 0; i < 4; ++i)
#pragma unroll
            for (int j = 0; j < 4; ++j)
                acc[i][j] = __builtin_amdgcn_mfma_f32_16x16x32_f16(aF[i], bF[j], acc[i][j], 0, 0, 0);
        __syncthreads();
    }

#pragma unroll
    for (int i = 0; i < 4; ++i) {
#pragma unroll
        for (int j = 0; j < 4; ++j) {
            int gr = m0 + wr * 64 + i * 16 + quad * 4;
            int gc = n0 + wc * 64 + j * 16 + m16;
            float bv = BIAS ? bias[gc] : 0.f;
#pragma unroll
            for (int r = 0; r < 4; ++r) {
                int row = gr + r;
                if (row < M) {
                    float v = acc[i][j][r] + bv;
                    if (RELU) v = v > 0.f ? v : 0.f;
                    C[(size_t)row * N + gc] = (_Float16)v;
                }
            }
        }
    }
}

// ---------------------------------------------------------------------------
// MFMA fp16 pair scorer: 128 pairs/block, N=128, K=384 in 3 regions of 128
// feat = [z[s] | z[d] | z[s]*z[d]]; out[p] = relu(feat@Wp1+bp1) . Wp2 + bp2
// ---------------------------------------------------------------------------
__global__ __launch_bounds__(256) void scorer_mfma_k(
        const _Float16* __restrict__ z16, const int* __restrict__ pairs,
        const _Float16* __restrict__ Wp1t, const float* __restrict__ bp1,
        const float* __restrict__ Wp2, const float* __restrict__ bp2,
        float* __restrict__ out, int P) {
    __shared__ _Float16 Fs[128][136];   // feat chunk [pair][k], +8 pad
    __shared__ _Float16 Ws[128][136];   // Wp1t chunk [n][k]
    __shared__ int sidx[128], didx[128];
    __shared__ float red[128][2];

    int t  = threadIdx.x;
    int p0 = blockIdx.x * 128;

    if (t < 128) {
        int p = p0 + t;
        if (p >= P) p = P - 1;
        sidx[t] = pairs[p];
        didx[t] = pairs[P + p];
    }
    __syncthreads();

    int lane = t & 63, wave = t >> 6;
    int quad = lane >> 4, m16 = lane & 15;
    int wr = wave >> 1, wc = wave & 1;

    floatx4 acc[4][4];
#pragma unroll
    for (int i = 0; i < 4; ++i)
#pragma unroll
        for (int j = 0; j < 4; ++j)
            acc[i][j] = (floatx4)0.f;

    int pr = t & 127;          // staging row (pair / n)
    int kh = (t >> 7) * 64;    // k-half offset 0 / 64

    for (int r = 0; r < 3; ++r) {
        // stage feat region
        {
            const _Float16* zs = &z16[(size_t)sidx[pr] * EMBED + kh];
            const _Float16* zd = &z16[(size_t)didx[pr] * EMBED + kh];
            half8v f[8];
            if (r == 0) {
#pragma unroll
                for (int i = 0; i < 8; ++i) f[i] = *(const half8v*)&zs[i * 8];
            } else if (r == 1) {
#pragma unroll
                for (int i = 0; i < 8; ++i) f[i] = *(const half8v*)&zd[i * 8];
            } else {
#pragma unroll
                for (int i = 0; i < 8; ++i) {
                    half8v a = *(const half8v*)&zs[i * 8];
                    half8v b = *(const half8v*)&zd[i * 8];
                    f[i] = a * b;
                }
            }
#pragma unroll
            for (int i = 0; i < 8; ++i)
                *(half8v*)&Fs[pr][kh + i * 8] = f[i];
        }
        // stage Wp1t region
        {
            const _Float16* wsrc = &Wp1t[(size_t)pr * 384 + r * 128 + kh];
#pragma unroll
            for (int i = 0; i < 8; ++i)
                *(half8v*)&Ws[pr][kh + i * 8] = *(const half8v*)&wsrc[i * 8];
        }
        __syncthreads();

#pragma unroll
        for (int k0 = 0; k0 < 128; k0 += 32) {
            half8v aF[4], bF[4];
#pragma unroll
            for (int i = 0; i < 4; ++i)
                aF[i] = *(const half8v*)&Fs[wr * 64 + i * 16 + m16][k0 + quad * 8];
#pragma unroll
            for (int j = 0; j < 4; ++j)
                bF[j] = *(const half8v*)&Ws[wc * 64 + j * 16 + m16][k0 + quad * 8];
#pragma unroll
            for (int i = 0; i < 4; ++i)
#pragma unroll
                for (int j = 0; j < 4; ++j)
                    acc[i][j] = __builtin_amdgcn_mfma_f32_16x16x32_f16(aF[i], bF[j], acc[i][j], 0, 0, 0);
        }
        __syncthreads();
    }

    // epilogue: relu(acc + bp1) . Wp2, shfl-reduce across the 16 col lanes
    float w2v[4], b1v[4];
#pragma unroll
    for (int j = 0; j < 4; ++j) {
        int col = wc * 64 + j * 16 + m16;
        w2v[j] = Wp2[col];
        b1v[j] = bp1[col];
    }
#pragma unroll
    for (int i = 0; i < 4; ++i) {
#pragma unroll
        for (int rr = 0; rr < 4; ++rr) {
            float partial = 0.f;
#pragma unroll
            for (int j = 0; j < 4; ++j) {
                float v = acc[i][j][rr] + b1v[j];
                v = v > 0.f ? v : 0.f;
                partial += v * w2v[j];
            }
#pragma unroll
            for (int off = 1; off < 16; off <<= 1)
                partial += __shfl_xor(partial, off, 64);
            if (m16 == 0)
                red[wr * 64 + i * 16 + quad * 4 + rr][wc] = partial;
        }
    }
    __syncthreads();
    if (t < 128) {
        int p = p0 + t;
        if (p < P) out[p] = red[t][0] + red[t][1] + bp2[0];
    }
}

// ---------------------------------------------------------------------------
// Launch
// ---------------------------------------------------------------------------
extern "C" void kernel_launch(void* const* d_in, const int* in_sizes, int n_in,
                              void* d_out, int out_size, void* d_ws, size_t ws_size,
                              hipStream_t stream) {
    const int*   node_type_ids = (const int*)d_in[0];
    const int*   rows          = (const int*)d_in[1];
    const int*   cols          = (const int*)d_in[2];
    const float* edge_vals     = (const float*)d_in[3];
    const int*   pairs         = (const int*)d_in[4];
    const float* node_emb      = (const float*)d_in[5];
    const float* type_emb      = (const float*)d_in[6];
    const float* W1            = (const float*)d_in[7];
    const float* b1            = (const float*)d_in[8];
    const float* W2            = (const float*)d_in[9];
    const float* b2            = (const float*)d_in[10];
    const float* Wp1           = (const float*)d_in[11];
    const float* bp1           = (const float*)d_in[12];
    const float* Wp2           = (const float*)d_in[13];
    const float* bp2           = (const float*)d_in[14];
    float* out = (float*)d_out;

    const size_t MB = 1ull << 20;
    char* ws = (char*)d_ws;
    int*      rp   = (int*)(ws);
    _Float16* x16  = (_Float16*)(ws + 4 * MB);
    _Float16* s1   = (_Float16*)(ws + 56 * MB);
    _Float16* h16  = (_Float16*)(ws + 108 * MB);
    _Float16* g16  = (_Float16*)(ws + 160 * MB);
    _Float16* z16  = (_Float16*)(ws + 186 * MB);
    _Float16* W1t  = (_Float16*)(ws + 212 * MB);
    _Float16* W2t  = (_Float16*)(ws + 213 * MB);
    _Float16* Wp1t = (_Float16*)(ws + 214 * MB);

    // prep
    build_rowptr_k<<<(N_NODES + 256) / 256, 256, 0, stream>>>(rows, rp, N_NODES, N_EDGES);
    build_x16_k<<<(N_NODES * 64 + 255) / 256, 256, 0, stream>>>(node_emb, type_emb,
                                                                node_type_ids, x16);
    transpose_w_k<<<(HIDDEN * HIDDEN + 255) / 256, 256, 0, stream>>>(W1, W1t, HIDDEN, HIDDEN);
    transpose_w_k<<<(HIDDEN * EMBED + 255) / 256, 256, 0, stream>>>(W2, W2t, HIDDEN, EMBED);
    transpose_wp1_k<<<EMBED, 3 * EMBED, 0, stream>>>(Wp1, Wp1t);

    // s1 = spmm(x16)
    spmm1_k<<<N_NODES / 4, 256, 0, stream>>>(rp, cols, edge_vals, x16, s1);

    // h = relu(s1 @ W1 + b1)
    {
        dim3 grid((N_NODES + 127) / 128, HIDDEN / 128);
        gemm16_k<true, true><<<grid, 256, 0, stream>>>(s1, W1t, b1, h16, N_NODES, HIDDEN);
    }

    // g = h @ W2   (z = spmm(g) + b2 by linearity)
    {
        dim3 grid((N_NODES + 127) / 128, EMBED / 128);
        gemm16_k<false, false><<<grid, 256, 0, stream>>>(h16, W2t, nullptr, g16, N_NODES, EMBED);
    }

    // z16 = spmm(g) + b2
    spmm2_k<<<N_NODES / 4, 256, 0, stream>>>(rp, cols, edge_vals, g16, b2, z16);

    // scorer
    scorer_mfma_k<<<(N_PAIRS + 127) / 128, 256, 0, stream>>>(z16, pairs, Wp1t, bp1,
                                                             Wp2, bp2, out, N_PAIRS);
}

// Round 3
// 642.970 us; speedup vs baseline: 1.0183x; 1.0183x over previous
//
#include <hip/hip_runtime.h>
#include <hip/hip_bf16.h>

#define N_NODES 100000
#define N_TYPES 10
#define N_EDGES 3200000
#define HIDDEN 256
#define EMBED 128
#define N_PAIRS 100000

typedef _Float16 half2v __attribute__((ext_vector_type(2)));
typedef _Float16 half4v __attribute__((ext_vector_type(4)));
typedef _Float16 half8v __attribute__((ext_vector_type(8)));
typedef float floatx4 __attribute__((ext_vector_type(4)));

#define GLOBAL_AS __attribute__((address_space(1)))
#define LDS_AS __attribute__((address_space(3)))

static __device__ __forceinline__ void async_copy16(const void* g, void* lds) {
    __builtin_amdgcn_global_load_lds((const GLOBAL_AS unsigned int*)g,
                                     (LDS_AS unsigned int*)(void*)lds, 16, 0, 0);
}

// ---------------------------------------------------------------------------
// row_ptr from sorted rows (binary search, no atomics)
// ---------------------------------------------------------------------------
__global__ void build_rowptr_k(const int* __restrict__ rows, int* __restrict__ rp,
                               int n_nodes, int n_edges) {
    int n = blockIdx.x * blockDim.x + threadIdx.x;
    if (n > n_nodes) return;
    int lo = 0, hi = n_edges;
    while (lo < hi) {
        int mid = (lo + hi) >> 1;
        if (rows[mid] < n) lo = mid + 1; else hi = mid;
    }
    rp[n] = lo;
}

// ---------------------------------------------------------------------------
// x16 planes: x16p[plane][n][0:128] = fp16(node_emb + type_emb[type]),
// plane = feature half. Split planes let spmm1 run as two passes whose
// per-pass gather footprint (25.6MB) has reuse distance < per-XCD L2.
// ---------------------------------------------------------------------------
__global__ void build_x16_k(const float* __restrict__ node_emb,
                            const float* __restrict__ type_emb,
                            const int* __restrict__ ntype,
                            _Float16* __restrict__ x16p) {
    int idx = blockIdx.x * blockDim.x + threadIdx.x;
    int n  = idx >> 6;
    if (n >= N_NODES) return;
    int f4 = (idx & 63) * 4;
    int t = ntype[n];
    float4 a = *(const float4*)&node_emb[(size_t)n * HIDDEN + f4];
    float4 b = *(const float4*)&type_emb[(size_t)t * HIDDEN + f4];
    half4v o;
    o.x = (_Float16)(a.x + b.x);
    o.y = (_Float16)(a.y + b.y);
    o.z = (_Float16)(a.z + b.z);
    o.w = (_Float16)(a.w + b.w);
    int plane = f4 >> 7;          // 0 / 1
    int po    = f4 & 127;
    *(half4v*)&x16p[((size_t)plane * N_NODES + n) * 128 + po] = o;
}

// ---------------------------------------------------------------------------
// Wt[n][k] = fp16(W[k][n])  for K=256 weights (W1, W2)
// ---------------------------------------------------------------------------
__global__ void transpose_w_k(const float* __restrict__ W, _Float16* __restrict__ Wt,
                              int K, int N) {
    int idx = blockIdx.x * blockDim.x + threadIdx.x;   // idx = n*256 + k
    if (idx >= K * N) return;
    int k = idx & 255;
    int n = idx >> 8;
    Wt[idx] = (_Float16)W[(size_t)k * N + n];
}

// Wp1 [384,128] -> Wp1t [128][384] fp16
__global__ void transpose_wp1_k(const float* __restrict__ W, _Float16* __restrict__ Wt) {
    int k = threadIdx.x;   // 0..383
    int n = blockIdx.x;    // 0..127
    Wt[n * 384 + k] = (_Float16)W[(size_t)k * EMBED + n];
}

// ---------------------------------------------------------------------------
// spmm1 pass: s1[n][fbase:fbase+128] = sum_e val[e] * xp[cols[e]][0:128]
// one wave/node, lane = 2 feats (4B gather); row index WAVE-UNIFORM so
// cols/vals stay in SGPRs; 16 edges (16 x 256B) in flight per wave.
// ---------------------------------------------------------------------------
__global__ void spmm1_pass_k(const int* __restrict__ rp, const int* __restrict__ cols,
                             const float* __restrict__ vals,
                             const _Float16* __restrict__ xp,
                             _Float16* __restrict__ s1, int fbase) {
    int wave = threadIdx.x >> 6, lane = threadIdx.x & 63;
    int n = blockIdx.x * 4 + wave;
    int e0 = rp[n], e1 = rp[n + 1];
    int fo = lane * 2;
    float ax = 0.f, ay = 0.f;
    int e = e0;
    for (; e + 16 <= e1; e += 16) {
        int c[16]; float v[16];
#pragma unroll
        for (int i = 0; i < 16; ++i) { c[i] = cols[e + i]; v[i] = vals[e + i]; }
        half2v h[16];
#pragma unroll
        for (int i = 0; i < 16; ++i)
            h[i] = *(const half2v*)&xp[(size_t)c[i] * 128 + fo];
#pragma unroll
        for (int i = 0; i < 16; ++i) {
            ax += v[i] * (float)h[i].x;
            ay += v[i] * (float)h[i].y;
        }
    }
    for (; e + 4 <= e1; e += 4) {
        int c[4]; float v[4];
#pragma unroll
        for (int i = 0; i < 4; ++i) { c[i] = cols[e + i]; v[i] = vals[e + i]; }
        half2v h[4];
#pragma unroll
        for (int i = 0; i < 4; ++i)
            h[i] = *(const half2v*)&xp[(size_t)c[i] * 128 + fo];
#pragma unroll
        for (int i = 0; i < 4; ++i) {
            ax += v[i] * (float)h[i].x;
            ay += v[i] * (float)h[i].y;
        }
    }
    for (; e < e1; ++e) {
        int c0 = cols[e]; float v0 = vals[e];
        half2v h0 = *(const half2v*)&xp[(size_t)c0 * 128 + fo];
        ax += v0 * (float)h0.x;
        ay += v0 * (float)h0.y;
    }
    half2v o;
    o.x = (_Float16)ax;
    o.y = (_Float16)ay;
    *(half2v*)&s1[(size_t)n * HIDDEN + fbase + fo] = o;
}

// ---------------------------------------------------------------------------
// spmm2: z16[n][0:128] fp16 = sum_e val[e] * g16[cols[e]][:] + b2
// one wave/node, lane = 2 feats (4B gather, wave-uniform row index);
// 16 edges in flight per wave.
// ---------------------------------------------------------------------------
__global__ void spmm2_k(const int* __restrict__ rp, const int* __restrict__ cols,
                        const float* __restrict__ vals,
                        const _Float16* __restrict__ g16,
                        const float* __restrict__ b2, _Float16* __restrict__ z16) {
    int wave = threadIdx.x >> 6, lane = threadIdx.x & 63;
    int n = blockIdx.x * 4 + wave;
    int e0 = rp[n], e1 = rp[n + 1];
    int fo = lane * 2;
    float ax = 0.f, ay = 0.f;
    int e = e0;
    for (; e + 16 <= e1; e += 16) {
        int c[16]; float v[16];
#pragma unroll
        for (int i = 0; i < 16; ++i) { c[i] = cols[e + i]; v[i] = vals[e + i]; }
        half2v h[16];
#pragma unroll
        for (int i = 0; i < 16; ++i)
            h[i] = *(const half2v*)&g16[(size_t)c[i] * EMBED + fo];
#pragma unroll
        for (int i = 0; i < 16; ++i) {
            ax += v[i] * (float)h[i].x;
            ay += v[i] * (float)h[i].y;
        }
    }
    for (; e + 4 <= e1; e += 4) {
        int c[4]; float v[4];
#pragma unroll
        for (int i = 0; i < 4; ++i) { c[i] = cols[e + i]; v[i] = vals[e + i]; }
        half2v h[4];
#pragma unroll
        for (int i = 0; i < 4; ++i)
            h[i] = *(const half2v*)&g16[(size_t)c[i] * EMBED + fo];
#pragma unroll
        for (int i = 0; i < 4; ++i) {
            ax += v[i] * (float)h[i].x;
            ay += v[i] * (float)h[i].y;
        }
    }
    for (; e < e1; ++e) {
        int c0 = cols[e]; float v0 = vals[e];
        half2v h0 = *(const half2v*)&g16[(size_t)c0 * EMBED + fo];
        ax += v0 * (float)h0.x;
        ay += v0 * (float)h0.y;
    }
    half2v o;
    o.x = (_Float16)(ax + b2[fo]);
    o.y = (_Float16)(ay + b2[fo + 1]);
    *(half2v*)&z16[(size_t)n * EMBED + fo] = o;
}

// ---------------------------------------------------------------------------
// fp16 MFMA GEMM: C16 = [relu](A @ Bt^T + bias), A [M,256], Bt [N,256]
// 128x128 tile, BK=32, 256 thr, global_load_lds width-16 staging
// ---------------------------------------------------------------------------
template <bool RELU, bool BIAS>
__global__ void gemm16_k(const _Float16* __restrict__ A,
                         const _Float16* __restrict__ Bt,
                         const float* __restrict__ bias,
                         _Float16* __restrict__ C,
                         int M, int N) {
    const int K = 256;
    __shared__ _Float16 As[128 * 32];
    __shared__ _Float16 Bs[128 * 32];

    int t = threadIdx.x;
    int lane = t & 63;
    int wave = t >> 6;
    int quad = lane >> 4;
    int m16 = lane & 15;
    int wr = wave >> 1, wc = wave & 1;
    int m0 = blockIdx.x * 128;
    int n0 = blockIdx.y * 128;

    int srow = t >> 2;
    int skoff = (t & 3) * 8;

    floatx4 acc[4][4];
#pragma unroll
    for (int i = 0; i < 4; ++i)
#pragma unroll
        for (int j = 0; j < 4; ++j)
            acc[i][j] = (floatx4)0.f;

    for (int k0 = 0; k0 < K; k0 += 32) {
        int ra0 = m0 + srow;       if (ra0 >= M) ra0 = M - 1;
        int ra1 = m0 + srow + 64;  if (ra1 >= M) ra1 = M - 1;
        async_copy16(&A[(size_t)ra0 * K + k0 + skoff], &As[srow * 32 + skoff]);
        async_copy16(&A[(size_t)ra1 * K + k0 + skoff], &As[(srow + 64) * 32 + skoff]);
        async_copy16(&Bt[(size_t)(n0 + srow) * K + k0 + skoff], &Bs[srow * 32 + skoff]);
        async_copy16(&Bt[(size_t)(n0 + srow + 64) * K + k0 + skoff], &Bs[(srow + 64) * 32 + skoff]);
        __syncthreads();

        half8v aF[4], bF[4];
#pragma unroll
        for (int i = 0; i < 4; ++i)
            aF[i] = *(const half8v*)&As[(wr * 64 + i * 16 + m16) * 32 + quad * 8];
#pragma unroll
        for (int j = 0; j < 4; ++j)
            bF[j] = *(const half8v*)&Bs[(wc * 64 + j * 16 + m16) * 32 + quad * 8];
#pragma unroll
        for (int i = 0; i < 4; ++i)
#pragma unroll
            for (int j = 0; j < 4; ++j)
                acc[i][j] = __builtin_amdgcn_mfma_f32_16x16x32_f16(aF[i], bF[j], acc[i][j], 0, 0, 0);
        __syncthreads();
    }

#pragma unroll
    for (int i = 0; i < 4; ++i) {
#pragma unroll
        for (int j = 0; j < 4; ++j) {
            int gr = m0 + wr * 64 + i * 16 + quad * 4;
            int gc = n0 + wc * 64 + j * 16 + m16;
            float bv = BIAS ? bias[gc] : 0.f;
#pragma unroll
            for (int r = 0; r < 4; ++r) {
                int row = gr + r;
                if (row < M) {
                    float v = acc[i][j][r] + bv;
                    if (RELU) v = v > 0.f ? v : 0.f;
                    C[(size_t)row * N + gc] = (_Float16)v;
                }
            }
        }
    }
}

// ---------------------------------------------------------------------------
// MFMA fp16 pair scorer: 128 pairs/block, N=128, K=384 in 3 regions of 128
// feat = [z[s] | z[d] | z[s]*z[d]]; out[p] = relu(feat@Wp1+bp1) . Wp2 + bp2
// ---------------------------------------------------------------------------
__global__ __launch_bounds__(256) void scorer_mfma_k(
        const _Float16* __restrict__ z16, const int* __restrict__ pairs,
        const _Float16* __restrict__ Wp1t, const float* __restrict__ bp1,
        const float* __restrict__ Wp2, const float* __restrict__ bp2,
        float* __restrict__ out, int P) {
    __shared__ _Float16 Fs[128][136];   // feat chunk [pair][k], +8 pad
    __shared__ _Float16 Ws[128][136];   // Wp1t chunk [n][k]
    __shared__ int sidx[128], didx[128];
    __shared__ float red[128][2];

    int t  = threadIdx.x;
    int p0 = blockIdx.x * 128;

    if (t < 128) {
        int p = p0 + t;
        if (p >= P) p = P - 1;
        sidx[t] = pairs[p];
        didx[t] = pairs[P + p];
    }
    __syncthreads();

    int lane = t & 63, wave = t >> 6;
    int quad = lane >> 4, m16 = lane & 15;
    int wr = wave >> 1, wc = wave & 1;

    floatx4 acc[4][4];
#pragma unroll
    for (int i = 0; i < 4; ++i)
#pragma unroll
        for (int j = 0; j < 4; ++j)
            acc[i][j] = (floatx4)0.f;

    int pr = t & 127;          // staging row (pair / n)
    int kh = (t >> 7) * 64;    // k-half offset 0 / 64

    for (int r = 0; r < 3; ++r) {
        // stage feat region
        {
            const _Float16* zs = &z16[(size_t)sidx[pr] * EMBED + kh];
            const _Float16* zd = &z16[(size_t)didx[pr] * EMBED + kh];
            half8v f[8];
            if (r == 0) {
#pragma unroll
                for (int i = 0; i < 8; ++i) f[i] = *(const half8v*)&zs[i * 8];
            } else if (r == 1) {
#pragma unroll
                for (int i = 0; i < 8; ++i) f[i] = *(const half8v*)&zd[i * 8];
            } else {
#pragma unroll
                for (int i = 0; i < 8; ++i) {
                    half8v a = *(const half8v*)&zs[i * 8];
                    half8v b = *(const half8v*)&zd[i * 8];
                    f[i] = a * b;
                }
            }
#pragma unroll
            for (int i = 0; i < 8; ++i)
                *(half8v*)&Fs[pr][kh + i * 8] = f[i];
        }
        // stage Wp1t region
        {
            const _Float16* wsrc = &Wp1t[(size_t)pr * 384 + r * 128 + kh];
#pragma unroll
            for (int i = 0; i < 8; ++i)
                *(half8v*)&Ws[pr][kh + i * 8] = *(const half8v*)&wsrc[i * 8];
        }
        __syncthreads();

#pragma unroll
        for (int k0 = 0; k0 < 128; k0 += 32) {
            half8v aF[4], bF[4];
#pragma unroll
            for (int i = 0; i < 4; ++i)
                aF[i] = *(const half8v*)&Fs[wr * 64 + i * 16 + m16][k0 + quad * 8];
#pragma unroll
            for (int j = 0; j < 4; ++j)
                bF[j] = *(const half8v*)&Ws[wc * 64 + j * 16 + m16][k0 + quad * 8];
#pragma unroll
            for (int i = 0; i < 4; ++i)
#pragma unroll
                for (int j = 0; j < 4; ++j)
                    acc[i][j] = __builtin_amdgcn_mfma_f32_16x16x32_f16(aF[i], bF[j], acc[i][j], 0, 0, 0);
        }
        __syncthreads();
    }

    // epilogue: relu(acc + bp1) . Wp2, shfl-reduce across the 16 col lanes
    float w2v[4], b1v[4];
#pragma unroll
    for (int j = 0; j < 4; ++j) {
        int col = wc * 64 + j * 16 + m16;
        w2v[j] = Wp2[col];
        b1v[j] = bp1[col];
    }
#pragma unroll
    for (int i = 0; i < 4; ++i) {
#pragma unroll
        for (int rr = 0; rr < 4; ++rr) {
            float partial = 0.f;
#pragma unroll
            for (int j = 0; j < 4; ++j) {
                float v = acc[i][j][rr] + b1v[j];
                v = v > 0.f ? v : 0.f;
                partial += v * w2v[j];
            }
#pragma unroll
            for (int off = 1; off < 16; off <<= 1)
                partial += __shfl_xor(partial, off, 64);
            if (m16 == 0)
                red[wr * 64 + i * 16 + quad * 4 + rr][wc] = partial;
        }
    }
    __syncthreads();
    if (t < 128) {
        int p = p0 + t;
        if (p < P) out[p] = red[t][0] + red[t][1] + bp2[0];
    }
}

// ---------------------------------------------------------------------------
// Launch
// ---------------------------------------------------------------------------
extern "C" void kernel_launch(void* const* d_in, const int* in_sizes, int n_in,
                              void* d_out, int out_size, void* d_ws, size_t ws_size,
                              hipStream_t stream) {
    const int*   node_type_ids = (const int*)d_in[0];
    const int*   rows          = (const int*)d_in[1];
    const int*   cols          = (const int*)d_in[2];
    const float* edge_vals     = (const float*)d_in[3];
    const int*   pairs         = (const int*)d_in[4];
    const float* node_emb      = (const float*)d_in[5];
    const float* type_emb      = (const float*)d_in[6];
    const float* W1            = (const float*)d_in[7];
    const float* b1            = (const float*)d_in[8];
    const float* W2            = (const float*)d_in[9];
    const float* b2            = (const float*)d_in[10];
    const float* Wp1           = (const float*)d_in[11];
    const float* bp1           = (const float*)d_in[12];
    const float* Wp2           = (const float*)d_in[13];
    const float* bp2           = (const float*)d_in[14];
    float* out = (float*)d_out;

    const size_t MB = 1ull << 20;
    char* ws = (char*)d_ws;
    int*      rp    = (int*)(ws);
    _Float16* x16p  = (_Float16*)(ws + 4 * MB);    // 2 planes x [N][128] = 51.2MB
    _Float16* s1    = (_Float16*)(ws + 56 * MB);
    _Float16* h16   = (_Float16*)(ws + 108 * MB);
    _Float16* g16   = (_Float16*)(ws + 160 * MB);
    _Float16* z16   = (_Float16*)(ws + 186 * MB);
    _Float16* W1t   = (_Float16*)(ws + 212 * MB);
    _Float16* W2t   = (_Float16*)(ws + 213 * MB);
    _Float16* Wp1t  = (_Float16*)(ws + 214 * MB);

    // prep
    build_rowptr_k<<<(N_NODES + 256) / 256, 256, 0, stream>>>(rows, rp, N_NODES, N_EDGES);
    build_x16_k<<<(N_NODES * 64 + 255) / 256, 256, 0, stream>>>(node_emb, type_emb,
                                                                node_type_ids, x16p);
    transpose_w_k<<<(HIDDEN * HIDDEN + 255) / 256, 256, 0, stream>>>(W1, W1t, HIDDEN, HIDDEN);
    transpose_w_k<<<(HIDDEN * EMBED + 255) / 256, 256, 0, stream>>>(W2, W2t, HIDDEN, EMBED);
    transpose_wp1_k<<<EMBED, 3 * EMBED, 0, stream>>>(Wp1, Wp1t);

    // s1 = spmm(x) in two feature-half passes (L2-resident footprint per pass)
    spmm1_pass_k<<<N_NODES / 4, 256, 0, stream>>>(rp, cols, edge_vals,
                                                  x16p, s1, 0);
    spmm1_pass_k<<<N_NODES / 4, 256, 0, stream>>>(rp, cols, edge_vals,
                                                  x16p + (size_t)N_NODES * 128, s1, 128);

    // h = relu(s1 @ W1 + b1)
    {
        dim3 grid((N_NODES + 127) / 128, HIDDEN / 128);
        gemm16_k<true, true><<<grid, 256, 0, stream>>>(s1, W1t, b1, h16, N_NODES, HIDDEN);
    }

    // g = h @ W2   (z = spmm(g) + b2 by linearity)
    {
        dim3 grid((N_NODES + 127) / 128, EMBED / 128);
        gemm16_k<false, false><<<grid, 256, 0, stream>>>(h16, W2t, nullptr, g16, N_NODES, EMBED);
    }

    // z16 = spmm(g) + b2
    spmm2_k<<<N_NODES / 4, 256, 0, stream>>>(rp, cols, edge_vals, g16, b2, z16);

    // scorer
    scorer_mfma_k<<<(N_PAIRS + 127) / 128, 256, 0, stream>>>(z16, pairs, Wp1t, bp1,
                                                             Wp2, bp2, out, N_PAIRS);
}

// Round 4
// 533.659 us; speedup vs baseline: 1.2268x; 1.2048x over previous
//
#include <hip/hip_runtime.h>
#include <hip/hip_bf16.h>

#define N_NODES 100000
#define N_TYPES 10
#define N_EDGES 3200000
#define HIDDEN 256
#define EMBED 128
#define N_PAIRS 100000

typedef _Float16 half2v __attribute__((ext_vector_type(2)));
typedef _Float16 half4v __attribute__((ext_vector_type(4)));
typedef _Float16 half8v __attribute__((ext_vector_type(8)));
typedef float floatx2 __attribute__((ext_vector_type(2)));
typedef float floatx4 __attribute__((ext_vector_type(4)));

#define GLOBAL_AS __attribute__((address_space(1)))
#define LDS_AS __attribute__((address_space(3)))

// fp8 pre-scale: x ~ N(0,0.028) -> x*16 ~ N(0,0.45) sits in e4m3 normal range
#define X8_SCALE 16.0f
#define X8_INV  (1.0f / 16.0f)

static __device__ __forceinline__ void async_copy16(const void* g, void* lds) {
    __builtin_amdgcn_global_load_lds((const GLOBAL_AS unsigned int*)g,
                                     (LDS_AS unsigned int*)(void*)lds, 16, 0, 0);
}

// ---------------------------------------------------------------------------
// row_ptr from sorted rows (binary search, no atomics)
// ---------------------------------------------------------------------------
__global__ void build_rowptr_k(const int* __restrict__ rows, int* __restrict__ rp,
                               int n_nodes, int n_edges) {
    int n = blockIdx.x * blockDim.x + threadIdx.x;
    if (n > n_nodes) return;
    int lo = 0, hi = n_edges;
    while (lo < hi) {
        int mid = (lo + hi) >> 1;
        if (rows[mid] < n) lo = mid + 1; else hi = mid;
    }
    rp[n] = lo;
}

// ---------------------------------------------------------------------------
// x8[n][f] = fp8_e4m3((node_emb[n][f] + type_emb[type[n]][f]) * 16)
// consumed ONLY by spmm1; halves its gather bytes (512B -> 256B per row)
// ---------------------------------------------------------------------------
__global__ void build_x8_k(const float* __restrict__ node_emb,
                           const float* __restrict__ type_emb,
                           const int* __restrict__ ntype,
                           unsigned char* __restrict__ x8) {
    int idx = blockIdx.x * blockDim.x + threadIdx.x;
    int n  = idx >> 6;
    if (n >= N_NODES) return;
    int f4 = (idx & 63) * 4;
    int t = ntype[n];
    float4 a = *(const float4*)&node_emb[(size_t)n * HIDDEN + f4];
    float4 b = *(const float4*)&type_emb[(size_t)t * HIDDEN + f4];
    int w = __builtin_amdgcn_cvt_pk_fp8_f32((a.x + b.x) * X8_SCALE,
                                            (a.y + b.y) * X8_SCALE, 0, false);
    w     = __builtin_amdgcn_cvt_pk_fp8_f32((a.z + b.z) * X8_SCALE,
                                            (a.w + b.w) * X8_SCALE, w, true);
    *(int*)&x8[(size_t)n * HIDDEN + f4] = w;
}

// ---------------------------------------------------------------------------
// Wt[n][k] = fp16(W[k][n])  for K=256 weights (W1, W2)
// ---------------------------------------------------------------------------
__global__ void transpose_w_k(const float* __restrict__ W, _Float16* __restrict__ Wt,
                              int K, int N) {
    int idx = blockIdx.x * blockDim.x + threadIdx.x;   // idx = n*256 + k
    if (idx >= K * N) return;
    int k = idx & 255;
    int n = idx >> 8;
    Wt[idx] = (_Float16)W[(size_t)k * N + n];
}

// Wp1 [384,128] -> Wp1t [128][384] fp16
__global__ void transpose_wp1_k(const float* __restrict__ W, _Float16* __restrict__ Wt) {
    int k = threadIdx.x;   // 0..383
    int n = blockIdx.x;    // 0..127
    Wt[n * 384 + k] = (_Float16)W[(size_t)k * EMBED + n];
}

// ---------------------------------------------------------------------------
// spmm1: s1[n][0:256] fp16 = (1/16) * sum_e val[e] * fp8dec(x8[cols[e]][:])
// one wave/node, lane = 4 feats (4B dword gather, one full 256B row per
// instruction, row index WAVE-UNIFORM -> cols/vals scalar);
// 16 edges (16 x 256B = 4KB) in flight per wave.
// ---------------------------------------------------------------------------
__global__ void spmm1_k(const int* __restrict__ rp, const int* __restrict__ cols,
                        const float* __restrict__ vals,
                        const unsigned char* __restrict__ x8,
                        _Float16* __restrict__ s1) {
    int wave = threadIdx.x >> 6, lane = threadIdx.x & 63;
    int n = blockIdx.x * 4 + wave;
    int e0 = rp[n], e1 = rp[n + 1];
    int fo = lane * 4;
    float a0 = 0.f, a1 = 0.f, a2 = 0.f, a3 = 0.f;
    int e = e0;
    for (; e + 16 <= e1; e += 16) {
        int c[16]; float v[16];
#pragma unroll
        for (int i = 0; i < 16; ++i) { c[i] = cols[e + i]; v[i] = vals[e + i]; }
        int w[16];
#pragma unroll
        for (int i = 0; i < 16; ++i)
            w[i] = *(const int*)&x8[(size_t)c[i] * HIDDEN + fo];
#pragma unroll
        for (int i = 0; i < 16; ++i) {
            floatx2 lo = __builtin_amdgcn_cvt_pk_f32_fp8(w[i], false);
            floatx2 hi = __builtin_amdgcn_cvt_pk_f32_fp8(w[i], true);
            a0 += v[i] * lo.x; a1 += v[i] * lo.y;
            a2 += v[i] * hi.x; a3 += v[i] * hi.y;
        }
    }
    for (; e + 4 <= e1; e += 4) {
        int c[4]; float v[4];
#pragma unroll
        for (int i = 0; i < 4; ++i) { c[i] = cols[e + i]; v[i] = vals[e + i]; }
        int w[4];
#pragma unroll
        for (int i = 0; i < 4; ++i)
            w[i] = *(const int*)&x8[(size_t)c[i] * HIDDEN + fo];
#pragma unroll
        for (int i = 0; i < 4; ++i) {
            floatx2 lo = __builtin_amdgcn_cvt_pk_f32_fp8(w[i], false);
            floatx2 hi = __builtin_amdgcn_cvt_pk_f32_fp8(w[i], true);
            a0 += v[i] * lo.x; a1 += v[i] * lo.y;
            a2 += v[i] * hi.x; a3 += v[i] * hi.y;
        }
    }
    for (; e < e1; ++e) {
        int c0 = cols[e]; float v0 = vals[e];
        int w0 = *(const int*)&x8[(size_t)c0 * HIDDEN + fo];
        floatx2 lo = __builtin_amdgcn_cvt_pk_f32_fp8(w0, false);
        floatx2 hi = __builtin_amdgcn_cvt_pk_f32_fp8(w0, true);
        a0 += v0 * lo.x; a1 += v0 * lo.y;
        a2 += v0 * hi.x; a3 += v0 * hi.y;
    }
    half4v o;
    o.x = (_Float16)(a0 * X8_INV); o.y = (_Float16)(a1 * X8_INV);
    o.z = (_Float16)(a2 * X8_INV); o.w = (_Float16)(a3 * X8_INV);
    *(half4v*)&s1[(size_t)n * HIDDEN + fo] = o;
}

// ---------------------------------------------------------------------------
// spmm2: z16[n][0:128] fp16 = sum_e val[e] * g16[cols[e]][:] + b2
// one wave/node, lane = 2 feats (4B gather, wave-uniform row index);
// 16 edges in flight per wave.
// ---------------------------------------------------------------------------
__global__ void spmm2_k(const int* __restrict__ rp, const int* __restrict__ cols,
                        const float* __restrict__ vals,
                        const _Float16* __restrict__ g16,
                        const float* __restrict__ b2, _Float16* __restrict__ z16) {
    int wave = threadIdx.x >> 6, lane = threadIdx.x & 63;
    int n = blockIdx.x * 4 + wave;
    int e0 = rp[n], e1 = rp[n + 1];
    int fo = lane * 2;
    float ax = 0.f, ay = 0.f;
    int e = e0;
    for (; e + 16 <= e1; e += 16) {
        int c[16]; float v[16];
#pragma unroll
        for (int i = 0; i < 16; ++i) { c[i] = cols[e + i]; v[i] = vals[e + i]; }
        half2v h[16];
#pragma unroll
        for (int i = 0; i < 16; ++i)
            h[i] = *(const half2v*)&g16[(size_t)c[i] * EMBED + fo];
#pragma unroll
        for (int i = 0; i < 16; ++i) {
            ax += v[i] * (float)h[i].x;
            ay += v[i] * (float)h[i].y;
        }
    }
    for (; e + 4 <= e1; e += 4) {
        int c[4]; float v[4];
#pragma unroll
        for (int i = 0; i < 4; ++i) { c[i] = cols[e + i]; v[i] = vals[e + i]; }
        half2v h[4];
#pragma unroll
        for (int i = 0; i < 4; ++i)
            h[i] = *(const half2v*)&g16[(size_t)c[i] * EMBED + fo];
#pragma unroll
        for (int i = 0; i < 4; ++i) {
            ax += v[i] * (float)h[i].x;
            ay += v[i] * (float)h[i].y;
        }
    }
    for (; e < e1; ++e) {
        int c0 = cols[e]; float v0 = vals[e];
        half2v h0 = *(const half2v*)&g16[(size_t)c0 * EMBED + fo];
        ax += v0 * (float)h0.x;
        ay += v0 * (float)h0.y;
    }
    half2v o;
    o.x = (_Float16)(ax + b2[fo]);
    o.y = (_Float16)(ay + b2[fo + 1]);
    *(half2v*)&z16[(size_t)n * EMBED + fo] = o;
}

// ---------------------------------------------------------------------------
// fp16 MFMA GEMM: C16 = [relu](A @ Bt^T + bias), A [M,256], Bt [N,256]
// 128x128 tile, BK=32, 256 thr, global_load_lds width-16 staging
// ---------------------------------------------------------------------------
template <bool RELU, bool BIAS>
__global__ void gemm16_k(const _Float16* __restrict__ A,
                         const _Float16* __restrict__ Bt,
                         const float* __restrict__ bias,
                         _Float16* __restrict__ C,
                         int M, int N) {
    const int K = 256;
    __shared__ _Float16 As[128 * 32];
    __shared__ _Float16 Bs[128 * 32];

    int t = threadIdx.x;
    int lane = t & 63;
    int wave = t >> 6;
    int quad = lane >> 4;
    int m16 = lane & 15;
    int wr = wave >> 1, wc = wave & 1;
    int m0 = blockIdx.x * 128;
    int n0 = blockIdx.y * 128;

    int srow = t >> 2;
    int skoff = (t & 3) * 8;

    floatx4 acc[4][4];
#pragma unroll
    for (int i = 0; i < 4; ++i)
#pragma unroll
        for (int j = 0; j < 4; ++j)
            acc[i][j] = (floatx4)0.f;

    for (int k0 = 0; k0 < K; k0 += 32) {
        int ra0 = m0 + srow;       if (ra0 >= M) ra0 = M - 1;
        int ra1 = m0 + srow + 64;  if (ra1 >= M) ra1 = M - 1;
        async_copy16(&A[(size_t)ra0 * K + k0 + skoff], &As[srow * 32 + skoff]);
        async_copy16(&A[(size_t)ra1 * K + k0 + skoff], &As[(srow + 64) * 32 + skoff]);
        async_copy16(&Bt[(size_t)(n0 + srow) * K + k0 + skoff], &Bs[srow * 32 + skoff]);
        async_copy16(&Bt[(size_t)(n0 + srow + 64) * K + k0 + skoff], &Bs[(srow + 64) * 32 + skoff]);
        __syncthreads();

        half8v aF[4], bF[4];
#pragma unroll
        for (int i = 0; i < 4; ++i)
            aF[i] = *(const half8v*)&As[(wr * 64 + i * 16 + m16) * 32 + quad * 8];
#pragma unroll
        for (int j = 0; j < 4; ++j)
            bF[j] = *(const half8v*)&Bs[(wc * 64 + j * 16 + m16) * 32 + quad * 8];
#pragma unroll
        for (int i = 0; i < 4; ++i)
#pragma unroll
            for (int j = 0; j < 4; ++j)
                acc[i][j] = __builtin_amdgcn_mfma_f32_16x16x32_f16(aF[i], bF[j], acc[i][j], 0, 0, 0);
        __syncthreads();
    }

#pragma unroll
    for (int i = 0; i < 4; ++i) {
#pragma unroll
        for (int j = 0; j < 4; ++j) {
            int gr = m0 + wr * 64 + i * 16 + quad * 4;
            int gc = n0 + wc * 64 + j * 16 + m16;
            float bv = BIAS ? bias[gc] : 0.f;
#pragma unroll
            for (int r = 0; r < 4; ++r) {
                int row = gr + r;
                if (row < M) {
                    float v = acc[i][j][r] + bv;
                    if (RELU) v = v > 0.f ? v : 0.f;
                    C[(size_t)row * N + gc] = (_Float16)v;
                }
            }
        }
    }
}

// ---------------------------------------------------------------------------
// MFMA fp16 pair scorer: 128 pairs/block, N=128, K=384 in 3 regions of 128
// feat = [z[s] | z[d] | z[s]*z[d]]; out[p] = relu(feat@Wp1+bp1) . Wp2 + bp2
// ---------------------------------------------------------------------------
__global__ __launch_bounds__(256) void scorer_mfma_k(
        const _Float16* __restrict__ z16, const int* __restrict__ pairs,
        const _Float16* __restrict__ Wp1t, const float* __restrict__ bp1,
        const float* __restrict__ Wp2, const float* __restrict__ bp2,
        float* __restrict__ out, int P) {
    __shared__ _Float16 Fs[128][136];   // feat chunk [pair][k], +8 pad
    __shared__ _Float16 Ws[128][136];   // Wp1t chunk [n][k]
    __shared__ int sidx[128], didx[128];
    __shared__ float red[128][2];

    int t  = threadIdx.x;
    int p0 = blockIdx.x * 128;

    if (t < 128) {
        int p = p0 + t;
        if (p >= P) p = P - 1;
        sidx[t] = pairs[p];
        didx[t] = pairs[P + p];
    }
    __syncthreads();

    int lane = t & 63, wave = t >> 6;
    int quad = lane >> 4, m16 = lane & 15;
    int wr = wave >> 1, wc = wave & 1;

    floatx4 acc[4][4];
#pragma unroll
    for (int i = 0; i < 4; ++i)
#pragma unroll
        for (int j = 0; j < 4; ++j)
            acc[i][j] = (floatx4)0.f;

    int pr = t & 127;          // staging row (pair / n)
    int kh = (t >> 7) * 64;    // k-half offset 0 / 64

    for (int r = 0; r < 3; ++r) {
        // stage feat region
        {
            const _Float16* zs = &z16[(size_t)sidx[pr] * EMBED + kh];
            const _Float16* zd = &z16[(size_t)didx[pr] * EMBED + kh];
            half8v f[8];
            if (r == 0) {
#pragma unroll
                for (int i = 0; i < 8; ++i) f[i] = *(const half8v*)&zs[i * 8];
            } else if (r == 1) {
#pragma unroll
                for (int i = 0; i < 8; ++i) f[i] = *(const half8v*)&zd[i * 8];
            } else {
#pragma unroll
                for (int i = 0; i < 8; ++i) {
                    half8v a = *(const half8v*)&zs[i * 8];
                    half8v b = *(const half8v*)&zd[i * 8];
                    f[i] = a * b;
                }
            }
#pragma unroll
            for (int i = 0; i < 8; ++i)
                *(half8v*)&Fs[pr][kh + i * 8] = f[i];
        }
        // stage Wp1t region
        {
            const _Float16* wsrc = &Wp1t[(size_t)pr * 384 + r * 128 + kh];
#pragma unroll
            for (int i = 0; i < 8; ++i)
                *(half8v*)&Ws[pr][kh + i * 8] = *(const half8v*)&wsrc[i * 8];
        }
        __syncthreads();

#pragma unroll
        for (int k0 = 0; k0 < 128; k0 += 32) {
            half8v aF[4], bF[4];
#pragma unroll
            for (int i = 0; i < 4; ++i)
                aF[i] = *(const half8v*)&Fs[wr * 64 + i * 16 + m16][k0 + quad * 8];
#pragma unroll
            for (int j = 0; j < 4; ++j)
                bF[j] = *(const half8v*)&Ws[wc * 64 + j * 16 + m16][k0 + quad * 8];
#pragma unroll
            for (int i = 0; i < 4; ++i)
#pragma unroll
                for (int j = 0; j < 4; ++j)
                    acc[i][j] = __builtin_amdgcn_mfma_f32_16x16x32_f16(aF[i], bF[j], acc[i][j], 0, 0, 0);
        }
        __syncthreads();
    }

    // epilogue: relu(acc + bp1) . Wp2, shfl-reduce across the 16 col lanes
    float w2v[4], b1v[4];
#pragma unroll
    for (int j = 0; j < 4; ++j) {
        int col = wc * 64 + j * 16 + m16;
        w2v[j] = Wp2[col];
        b1v[j] = bp1[col];
    }
#pragma unroll
    for (int i = 0; i < 4; ++i) {
#pragma unroll
        for (int rr = 0; rr < 4; ++rr) {
            float partial = 0.f;
#pragma unroll
            for (int j = 0; j < 4; ++j) {
                float v = acc[i][j][rr] + b1v[j];
                v = v > 0.f ? v : 0.f;
                partial += v * w2v[j];
            }
#pragma unroll
            for (int off = 1; off < 16; off <<= 1)
                partial += __shfl_xor(partial, off, 64);
            if (m16 == 0)
                red[wr * 64 + i * 16 + quad * 4 + rr][wc] = partial;
        }
    }
    __syncthreads();
    if (t < 128) {
        int p = p0 + t;
        if (p < P) out[p] = red[t][0] + red[t][1] + bp2[0];
    }
}

// ---------------------------------------------------------------------------
// Launch
// ---------------------------------------------------------------------------
extern "C" void kernel_launch(void* const* d_in, const int* in_sizes, int n_in,
                              void* d_out, int out_size, void* d_ws, size_t ws_size,
                              hipStream_t stream) {
    const int*   node_type_ids = (const int*)d_in[0];
    const int*   rows          = (const int*)d_in[1];
    const int*   cols          = (const int*)d_in[2];
    const float* edge_vals     = (const float*)d_in[3];
    const int*   pairs         = (const int*)d_in[4];
    const float* node_emb      = (const float*)d_in[5];
    const float* type_emb      = (const float*)d_in[6];
    const float* W1            = (const float*)d_in[7];
    const float* b1            = (const float*)d_in[8];
    const float* W2            = (const float*)d_in[9];
    const float* b2            = (const float*)d_in[10];
    const float* Wp1           = (const float*)d_in[11];
    const float* bp1           = (const float*)d_in[12];
    const float* Wp2           = (const float*)d_in[13];
    const float* bp2           = (const float*)d_in[14];
    float* out = (float*)d_out;

    const size_t MB = 1ull << 20;
    char* ws = (char*)d_ws;
    int*      rp   = (int*)(ws);
    unsigned char* x8 = (unsigned char*)(ws + 4 * MB);   // [N][256] fp8 = 25.6MB
    _Float16* s1   = (_Float16*)(ws + 56 * MB);
    _Float16* h16  = (_Float16*)(ws + 108 * MB);
    _Float16* g16  = (_Float16*)(ws + 160 * MB);
    _Float16* z16  = (_Float16*)(ws + 186 * MB);
    _Float16* W1t  = (_Float16*)(ws + 212 * MB);
    _Float16* W2t  = (_Float16*)(ws + 213 * MB);
    _Float16* Wp1t = (_Float16*)(ws + 214 * MB);

    // prep
    build_rowptr_k<<<(N_NODES + 256) / 256, 256, 0, stream>>>(rows, rp, N_NODES, N_EDGES);
    build_x8_k<<<(N_NODES * 64 + 255) / 256, 256, 0, stream>>>(node_emb, type_emb,
                                                               node_type_ids, x8);
    transpose_w_k<<<(HIDDEN * HIDDEN + 255) / 256, 256, 0, stream>>>(W1, W1t, HIDDEN, HIDDEN);
    transpose_w_k<<<(HIDDEN * EMBED + 255) / 256, 256, 0, stream>>>(W2, W2t, HIDDEN, EMBED);
    transpose_wp1_k<<<EMBED, 3 * EMBED, 0, stream>>>(Wp1, Wp1t);

    // s1 = spmm(x8)  (fp8 gather payload, x16 pre-scale folded out at store)
    spmm1_k<<<N_NODES / 4, 256, 0, stream>>>(rp, cols, edge_vals, x8, s1);

    // h = relu(s1 @ W1 + b1)
    {
        dim3 grid((N_NODES + 127) / 128, HIDDEN / 128);
        gemm16_k<true, true><<<grid, 256, 0, stream>>>(s1, W1t, b1, h16, N_NODES, HIDDEN);
    }

    // g = h @ W2   (z = spmm(g) + b2 by linearity)
    {
        dim3 grid((N_NODES + 127) / 128, EMBED / 128);
        gemm16_k<false, false><<<grid, 256, 0, stream>>>(h16, W2t, nullptr, g16, N_NODES, EMBED);
    }

    // z16 = spmm(g) + b2
    spmm2_k<<<N_NODES / 4, 256, 0, stream>>>(rp, cols, edge_vals, g16, b2, z16);

    // scorer
    scorer_mfma_k<<<(N_PAIRS + 127) / 128, 256, 0, stream>>>(z16, pairs, Wp1t, bp1,
                                                             Wp2, bp2, out, N_PAIRS);
}

// Round 5
// 510.240 us; speedup vs baseline: 1.2832x; 1.0459x over previous
//
#include <hip/hip_runtime.h>
#include <hip/hip_bf16.h>

#define N_NODES 100000
#define N_TYPES 10
#define N_EDGES 3200000
#define HIDDEN 256
#define EMBED 128
#define N_PAIRS 100000

typedef _Float16 half2v __attribute__((ext_vector_type(2)));
typedef _Float16 half4v __attribute__((ext_vector_type(4)));
typedef _Float16 half8v __attribute__((ext_vector_type(8)));
typedef float floatx2 __attribute__((ext_vector_type(2)));
typedef float floatx4 __attribute__((ext_vector_type(4)));

#define GLOBAL_AS __attribute__((address_space(1)))
#define LDS_AS __attribute__((address_space(3)))

// fp8 pre-scales: keep quantized values in e4m3 normal range
#define X8_SCALE 16.0f      // x ~ N(0,0.028) -> 0.45
#define X8_INV  (1.0f / 16.0f)
#define G8_SCALE 64.0f      // g ~ N(0,0.01)  -> 0.64
#define G8_INV  (1.0f / 64.0f)

static __device__ __forceinline__ void async_copy16(const void* g, void* lds) {
    __builtin_amdgcn_global_load_lds((const GLOBAL_AS unsigned int*)g,
                                     (LDS_AS unsigned int*)(void*)lds, 16, 0, 0);
}

// ---------------------------------------------------------------------------
// row_ptr from sorted rows (binary search, no atomics)
// ---------------------------------------------------------------------------
__global__ void build_rowptr_k(const int* __restrict__ rows, int* __restrict__ rp,
                               int n_nodes, int n_edges) {
    int n = blockIdx.x * blockDim.x + threadIdx.x;
    if (n > n_nodes) return;
    int lo = 0, hi = n_edges;
    while (lo < hi) {
        int mid = (lo + hi) >> 1;
        if (rows[mid] < n) lo = mid + 1; else hi = mid;
    }
    rp[n] = lo;
}

// ---------------------------------------------------------------------------
// x8[n][f] = fp8_e4m3((node_emb[n][f] + type_emb[type[n]][f]) * 16)
// consumed ONLY by spmm1; halves its gather bytes (512B -> 256B per row)
// ---------------------------------------------------------------------------
__global__ void build_x8_k(const float* __restrict__ node_emb,
                           const float* __restrict__ type_emb,
                           const int* __restrict__ ntype,
                           unsigned char* __restrict__ x8) {
    int idx = blockIdx.x * blockDim.x + threadIdx.x;
    int n  = idx >> 6;
    if (n >= N_NODES) return;
    int f4 = (idx & 63) * 4;
    int t = ntype[n];
    float4 a = *(const float4*)&node_emb[(size_t)n * HIDDEN + f4];
    float4 b = *(const float4*)&type_emb[(size_t)t * HIDDEN + f4];
    int w = __builtin_amdgcn_cvt_pk_fp8_f32((a.x + b.x) * X8_SCALE,
                                            (a.y + b.y) * X8_SCALE, 0, false);
    w     = __builtin_amdgcn_cvt_pk_fp8_f32((a.z + b.z) * X8_SCALE,
                                            (a.w + b.w) * X8_SCALE, w, true);
    *(int*)&x8[(size_t)n * HIDDEN + f4] = w;
}

// ---------------------------------------------------------------------------
// Wt[n][k] = fp16(W[k][n])  for K=256 weights (W1, W2)
// ---------------------------------------------------------------------------
__global__ void transpose_w_k(const float* __restrict__ W, _Float16* __restrict__ Wt,
                              int K, int N) {
    int idx = blockIdx.x * blockDim.x + threadIdx.x;   // idx = n*256 + k
    if (idx >= K * N) return;
    int k = idx & 255;
    int n = idx >> 8;
    Wt[idx] = (_Float16)W[(size_t)k * N + n];
}

// Wp1 [384,128] -> Wp1t [128][384] fp16
__global__ void transpose_wp1_k(const float* __restrict__ W, _Float16* __restrict__ Wt) {
    int k = threadIdx.x;   // 0..383
    int n = blockIdx.x;    // 0..127
    Wt[n * 384 + k] = (_Float16)W[(size_t)k * EMBED + n];
}

// ---------------------------------------------------------------------------
// spmm1: s1[n][0:256] fp16 = (1/16) * sum_e val[e] * fp8dec(x8[cols[e]][:])
// one wave/node, lane = 4 feats (4B dword gather, one full 256B row per
// instruction, row index WAVE-UNIFORM -> cols/vals scalar);
// 16 edges (16 x 256B = 4KB) in flight per wave.
// ---------------------------------------------------------------------------
__global__ void spmm1_k(const int* __restrict__ rp, const int* __restrict__ cols,
                        const float* __restrict__ vals,
                        const unsigned char* __restrict__ x8,
                        _Float16* __restrict__ s1) {
    int wave = threadIdx.x >> 6, lane = threadIdx.x & 63;
    int n = blockIdx.x * 4 + wave;
    int e0 = rp[n], e1 = rp[n + 1];
    int fo = lane * 4;
    float a0 = 0.f, a1 = 0.f, a2 = 0.f, a3 = 0.f;
    int e = e0;
    for (; e + 16 <= e1; e += 16) {
        int c[16]; float v[16];
#pragma unroll
        for (int i = 0; i < 16; ++i) { c[i] = cols[e + i]; v[i] = vals[e + i]; }
        int w[16];
#pragma unroll
        for (int i = 0; i < 16; ++i)
            w[i] = *(const int*)&x8[(size_t)c[i] * HIDDEN + fo];
#pragma unroll
        for (int i = 0; i < 16; ++i) {
            floatx2 lo = __builtin_amdgcn_cvt_pk_f32_fp8(w[i], false);
            floatx2 hi = __builtin_amdgcn_cvt_pk_f32_fp8(w[i], true);
            a0 += v[i] * lo.x; a1 += v[i] * lo.y;
            a2 += v[i] * hi.x; a3 += v[i] * hi.y;
        }
    }
    for (; e + 4 <= e1; e += 4) {
        int c[4]; float v[4];
#pragma unroll
        for (int i = 0; i < 4; ++i) { c[i] = cols[e + i]; v[i] = vals[e + i]; }
        int w[4];
#pragma unroll
        for (int i = 0; i < 4; ++i)
            w[i] = *(const int*)&x8[(size_t)c[i] * HIDDEN + fo];
#pragma unroll
        for (int i = 0; i < 4; ++i) {
            floatx2 lo = __builtin_amdgcn_cvt_pk_f32_fp8(w[i], false);
            floatx2 hi = __builtin_amdgcn_cvt_pk_f32_fp8(w[i], true);
            a0 += v[i] * lo.x; a1 += v[i] * lo.y;
            a2 += v[i] * hi.x; a3 += v[i] * hi.y;
        }
    }
    for (; e < e1; ++e) {
        int c0 = cols[e]; float v0 = vals[e];
        int w0 = *(const int*)&x8[(size_t)c0 * HIDDEN + fo];
        floatx2 lo = __builtin_amdgcn_cvt_pk_f32_fp8(w0, false);
        floatx2 hi = __builtin_amdgcn_cvt_pk_f32_fp8(w0, true);
        a0 += v0 * lo.x; a1 += v0 * lo.y;
        a2 += v0 * hi.x; a3 += v0 * hi.y;
    }
    half4v o;
    o.x = (_Float16)(a0 * X8_INV); o.y = (_Float16)(a1 * X8_INV);
    o.z = (_Float16)(a2 * X8_INV); o.w = (_Float16)(a3 * X8_INV);
    *(half4v*)&s1[(size_t)n * HIDDEN + fo] = o;
}

// ---------------------------------------------------------------------------
// spmm2: z16[n][0:128] fp16 = (1/64) * sum_e val[e] * fp8dec(g8[cols[e]][:]) + b2
// one wave/node, lane = 2 feats (2B ushort gather, one full 128B row per
// instruction, wave-uniform row index); 16 edges (2KB) in flight per wave.
// ---------------------------------------------------------------------------
__global__ void spmm2_k(const int* __restrict__ rp, const int* __restrict__ cols,
                        const float* __restrict__ vals,
                        const unsigned char* __restrict__ g8,
                        const float* __restrict__ b2, _Float16* __restrict__ z16) {
    int wave = threadIdx.x >> 6, lane = threadIdx.x & 63;
    int n = blockIdx.x * 4 + wave;
    int e0 = rp[n], e1 = rp[n + 1];
    int fo = lane * 2;
    float ax = 0.f, ay = 0.f;
    int e = e0;
    for (; e + 16 <= e1; e += 16) {
        int c[16]; float v[16];
#pragma unroll
        for (int i = 0; i < 16; ++i) { c[i] = cols[e + i]; v[i] = vals[e + i]; }
        unsigned short w[16];
#pragma unroll
        for (int i = 0; i < 16; ++i)
            w[i] = *(const unsigned short*)&g8[(size_t)c[i] * EMBED + fo];
#pragma unroll
        for (int i = 0; i < 16; ++i) {
            floatx2 d = __builtin_amdgcn_cvt_pk_f32_fp8((int)w[i], false);
            ax += v[i] * d.x;
            ay += v[i] * d.y;
        }
    }
    for (; e + 4 <= e1; e += 4) {
        int c[4]; float v[4];
#pragma unroll
        for (int i = 0; i < 4; ++i) { c[i] = cols[e + i]; v[i] = vals[e + i]; }
        unsigned short w[4];
#pragma unroll
        for (int i = 0; i < 4; ++i)
            w[i] = *(const unsigned short*)&g8[(size_t)c[i] * EMBED + fo];
#pragma unroll
        for (int i = 0; i < 4; ++i) {
            floatx2 d = __builtin_amdgcn_cvt_pk_f32_fp8((int)w[i], false);
            ax += v[i] * d.x;
            ay += v[i] * d.y;
        }
    }
    for (; e < e1; ++e) {
        int c0 = cols[e]; float v0 = vals[e];
        unsigned short w0 = *(const unsigned short*)&g8[(size_t)c0 * EMBED + fo];
        floatx2 d = __builtin_amdgcn_cvt_pk_f32_fp8((int)w0, false);
        ax += v0 * d.x;
        ay += v0 * d.y;
    }
    half2v o;
    o.x = (_Float16)(ax * G8_INV + b2[fo]);
    o.y = (_Float16)(ay * G8_INV + b2[fo + 1]);
    *(half2v*)&z16[(size_t)n * EMBED + fo] = o;
}

// ---------------------------------------------------------------------------
// fp16 MFMA GEMM: C = [relu](A @ Bt^T + bias), A [M,256], Bt [N,256]
// 128x128 tile, BK=32, 256 thr, global_load_lds width-16 staging.
// FP8OUT: store fp8_e4m3(v * 64) bytes instead of fp16 (for g -> spmm2).
// ---------------------------------------------------------------------------
template <bool RELU, bool BIAS, bool FP8OUT>
__global__ void gemm16_k(const _Float16* __restrict__ A,
                         const _Float16* __restrict__ Bt,
                         const float* __restrict__ bias,
                         void* __restrict__ Cout,
                         int M, int N) {
    const int K = 256;
    __shared__ _Float16 As[128 * 32];
    __shared__ _Float16 Bs[128 * 32];

    int t = threadIdx.x;
    int lane = t & 63;
    int wave = t >> 6;
    int quad = lane >> 4;
    int m16 = lane & 15;
    int wr = wave >> 1, wc = wave & 1;
    int m0 = blockIdx.x * 128;
    int n0 = blockIdx.y * 128;

    int srow = t >> 2;
    int skoff = (t & 3) * 8;

    floatx4 acc[4][4];
#pragma unroll
    for (int i = 0; i < 4; ++i)
#pragma unroll
        for (int j = 0; j < 4; ++j)
            acc[i][j] = (floatx4)0.f;

    for (int k0 = 0; k0 < K; k0 += 32) {
        int ra0 = m0 + srow;       if (ra0 >= M) ra0 = M - 1;
        int ra1 = m0 + srow + 64;  if (ra1 >= M) ra1 = M - 1;
        async_copy16(&A[(size_t)ra0 * K + k0 + skoff], &As[srow * 32 + skoff]);
        async_copy16(&A[(size_t)ra1 * K + k0 + skoff], &As[(srow + 64) * 32 + skoff]);
        async_copy16(&Bt[(size_t)(n0 + srow) * K + k0 + skoff], &Bs[srow * 32 + skoff]);
        async_copy16(&Bt[(size_t)(n0 + srow + 64) * K + k0 + skoff], &Bs[(srow + 64) * 32 + skoff]);
        __syncthreads();

        half8v aF[4], bF[4];
#pragma unroll
        for (int i = 0; i < 4; ++i)
            aF[i] = *(const half8v*)&As[(wr * 64 + i * 16 + m16) * 32 + quad * 8];
#pragma unroll
        for (int j = 0; j < 4; ++j)
            bF[j] = *(const half8v*)&Bs[(wc * 64 + j * 16 + m16) * 32 + quad * 8];
#pragma unroll
        for (int i = 0; i < 4; ++i)
#pragma unroll
            for (int j = 0; j < 4; ++j)
                acc[i][j] = __builtin_amdgcn_mfma_f32_16x16x32_f16(aF[i], bF[j], acc[i][j], 0, 0, 0);
        __syncthreads();
    }

#pragma unroll
    for (int i = 0; i < 4; ++i) {
#pragma unroll
        for (int j = 0; j < 4; ++j) {
            int gr = m0 + wr * 64 + i * 16 + quad * 4;
            int gc = n0 + wc * 64 + j * 16 + m16;
            float bv = BIAS ? bias[gc] : 0.f;
#pragma unroll
            for (int r = 0; r < 4; ++r) {
                int row = gr + r;
                if (row < M) {
                    float v = acc[i][j][r] + bv;
                    if (RELU) v = v > 0.f ? v : 0.f;
                    if (FP8OUT) {
                        float sv = v * G8_SCALE;
                        int w = __builtin_amdgcn_cvt_pk_fp8_f32(sv, sv, 0, false);
                        ((unsigned char*)Cout)[(size_t)row * N + gc] = (unsigned char)(w & 0xFF);
                    } else {
                        ((_Float16*)Cout)[(size_t)row * N + gc] = (_Float16)v;
                    }
                }
            }
        }
    }
}

// ---------------------------------------------------------------------------
// MFMA fp16 pair scorer: 128 pairs/block, N=128, K=384 in 3 regions of 128
// feat = [z[s] | z[d] | z[s]*z[d]]; out[p] = relu(feat@Wp1+bp1) . Wp2 + bp2
// ---------------------------------------------------------------------------
__global__ __launch_bounds__(256) void scorer_mfma_k(
        const _Float16* __restrict__ z16, const int* __restrict__ pairs,
        const _Float16* __restrict__ Wp1t, const float* __restrict__ bp1,
        const float* __restrict__ Wp2, const float* __restrict__ bp2,
        float* __restrict__ out, int P) {
    __shared__ _Float16 Fs[128][136];   // feat chunk [pair][k], +8 pad
    __shared__ _Float16 Ws[128][136];   // Wp1t chunk [n][k]
    __shared__ int sidx[128], didx[128];
    __shared__ float red[128][2];

    int t  = threadIdx.x;
    int p0 = blockIdx.x * 128;

    if (t < 128) {
        int p = p0 + t;
        if (p >= P) p = P - 1;
        sidx[t] = pairs[p];
        didx[t] = pairs[P + p];
    }
    __syncthreads();

    int lane = t & 63, wave = t >> 6;
    int quad = lane >> 4, m16 = lane & 15;
    int wr = wave >> 1, wc = wave & 1;

    floatx4 acc[4][4];
#pragma unroll
    for (int i = 0; i < 4; ++i)
#pragma unroll
        for (int j = 0; j < 4; ++j)
            acc[i][j] = (floatx4)0.f;

    int pr = t & 127;          // staging row (pair / n)
    int kh = (t >> 7) * 64;    // k-half offset 0 / 64

    for (int r = 0; r < 3; ++r) {
        // stage feat region
        {
            const _Float16* zs = &z16[(size_t)sidx[pr] * EMBED + kh];
            const _Float16* zd = &z16[(size_t)didx[pr] * EMBED + kh];
            half8v f[8];
            if (r == 0) {
#pragma unroll
                for (int i = 0; i < 8; ++i) f[i] = *(const half8v*)&zs[i * 8];
            } else if (r == 1) {
#pragma unroll
                for (int i = 0; i < 8; ++i) f[i] = *(const half8v*)&zd[i * 8];
            } else {
#pragma unroll
                for (int i = 0; i < 8; ++i) {
                    half8v a = *(const half8v*)&zs[i * 8];
                    half8v b = *(const half8v*)&zd[i * 8];
                    f[i] = a * b;
                }
            }
#pragma unroll
            for (int i = 0; i < 8; ++i)
                *(half8v*)&Fs[pr][kh + i * 8] = f[i];
        }
        // stage Wp1t region
        {
            const _Float16* wsrc = &Wp1t[(size_t)pr * 384 + r * 128 + kh];
#pragma unroll
            for (int i = 0; i < 8; ++i)
                *(half8v*)&Ws[pr][kh + i * 8] = *(const half8v*)&wsrc[i * 8];
        }
        __syncthreads();

#pragma unroll
        for (int k0 = 0; k0 < 128; k0 += 32) {
            half8v aF[4], bF[4];
#pragma unroll
            for (int i = 0; i < 4; ++i)
                aF[i] = *(const half8v*)&Fs[wr * 64 + i * 16 + m16][k0 + quad * 8];
#pragma unroll
            for (int j = 0; j < 4; ++j)
                bF[j] = *(const half8v*)&Ws[wc * 64 + j * 16 + m16][k0 + quad * 8];
#pragma unroll
            for (int i = 0; i < 4; ++i)
#pragma unroll
                for (int j = 0; j < 4; ++j)
                    acc[i][j] = __builtin_amdgcn_mfma_f32_16x16x32_f16(aF[i], bF[j], acc[i][j], 0, 0, 0);
        }
        __syncthreads();
    }

    // epilogue: relu(acc + bp1) . Wp2, shfl-reduce across the 16 col lanes
    float w2v[4], b1v[4];
#pragma unroll
    for (int j = 0; j < 4; ++j) {
        int col = wc * 64 + j * 16 + m16;
        w2v[j] = Wp2[col];
        b1v[j] = bp1[col];
    }
#pragma unroll
    for (int i = 0; i < 4; ++i) {
#pragma unroll
        for (int rr = 0; rr < 4; ++rr) {
            float partial = 0.f;
#pragma unroll
            for (int j = 0; j < 4; ++j) {
                float v = acc[i][j][rr] + b1v[j];
                v = v > 0.f ? v : 0.f;
                partial += v * w2v[j];
            }
#pragma unroll
            for (int off = 1; off < 16; off <<= 1)
                partial += __shfl_xor(partial, off, 64);
            if (m16 == 0)
                red[wr * 64 + i * 16 + quad * 4 + rr][wc] = partial;
        }
    }
    __syncthreads();
    if (t < 128) {
        int p = p0 + t;
        if (p < P) out[p] = red[t][0] + red[t][1] + bp2[0];
    }
}

// ---------------------------------------------------------------------------
// Launch
// ---------------------------------------------------------------------------
extern "C" void kernel_launch(void* const* d_in, const int* in_sizes, int n_in,
                              void* d_out, int out_size, void* d_ws, size_t ws_size,
                              hipStream_t stream) {
    const int*   node_type_ids = (const int*)d_in[0];
    const int*   rows          = (const int*)d_in[1];
    const int*   cols          = (const int*)d_in[2];
    const float* edge_vals     = (const float*)d_in[3];
    const int*   pairs         = (const int*)d_in[4];
    const float* node_emb      = (const float*)d_in[5];
    const float* type_emb      = (const float*)d_in[6];
    const float* W1            = (const float*)d_in[7];
    const float* b1            = (const float*)d_in[8];
    const float* W2            = (const float*)d_in[9];
    const float* b2            = (const float*)d_in[10];
    const float* Wp1           = (const float*)d_in[11];
    const float* bp1           = (const float*)d_in[12];
    const float* Wp2           = (const float*)d_in[13];
    const float* bp2           = (const float*)d_in[14];
    float* out = (float*)d_out;

    const size_t MB = 1ull << 20;
    char* ws = (char*)d_ws;
    int*      rp   = (int*)(ws);
    unsigned char* x8 = (unsigned char*)(ws + 4 * MB);   // [N][256] fp8 = 25.6MB
    _Float16* s1   = (_Float16*)(ws + 56 * MB);
    _Float16* h16  = (_Float16*)(ws + 108 * MB);
    unsigned char* g8 = (unsigned char*)(ws + 160 * MB); // [N][128] fp8 = 12.8MB
    _Float16* z16  = (_Float16*)(ws + 186 * MB);
    _Float16* W1t  = (_Float16*)(ws + 212 * MB);
    _Float16* W2t  = (_Float16*)(ws + 213 * MB);
    _Float16* Wp1t = (_Float16*)(ws + 214 * MB);

    // prep
    build_rowptr_k<<<(N_NODES + 256) / 256, 256, 0, stream>>>(rows, rp, N_NODES, N_EDGES);
    build_x8_k<<<(N_NODES * 64 + 255) / 256, 256, 0, stream>>>(node_emb, type_emb,
                                                               node_type_ids, x8);
    transpose_w_k<<<(HIDDEN * HIDDEN + 255) / 256, 256, 0, stream>>>(W1, W1t, HIDDEN, HIDDEN);
    transpose_w_k<<<(HIDDEN * EMBED + 255) / 256, 256, 0, stream>>>(W2, W2t, HIDDEN, EMBED);
    transpose_wp1_k<<<EMBED, 3 * EMBED, 0, stream>>>(Wp1, Wp1t);

    // s1 = spmm(x8)  (fp8 gather payload, x16 pre-scale folded out at store)
    spmm1_k<<<N_NODES / 4, 256, 0, stream>>>(rp, cols, edge_vals, x8, s1);

    // h = relu(s1 @ W1 + b1)
    {
        dim3 grid((N_NODES + 127) / 128, HIDDEN / 128);
        gemm16_k<true, true, false><<<grid, 256, 0, stream>>>(s1, W1t, b1, h16, N_NODES, HIDDEN);
    }

    // g8 = fp8(h @ W2 * 64)   (z = spmm(g) + b2 by linearity)
    {
        dim3 grid((N_NODES + 127) / 128, EMBED / 128);
        gemm16_k<false, false, true><<<grid, 256, 0, stream>>>(h16, W2t, nullptr, g8, N_NODES, EMBED);
    }

    // z16 = (1/64) * spmm(g8) + b2
    spmm2_k<<<N_NODES / 4, 256, 0, stream>>>(rp, cols, edge_vals, g8, b2, z16);

    // scorer
    scorer_mfma_k<<<(N_PAIRS + 127) / 128, 256, 0, stream>>>(z16, pairs, Wp1t, bp1,
                                                             Wp2, bp2, out, N_PAIRS);
}

// Round 6
// 481.191 us; speedup vs baseline: 1.3606x; 1.0604x over previous
//
#include <hip/hip_runtime.h>
#include <hip/hip_bf16.h>

#define N_NODES 100000
#define N_TYPES 10
#define N_EDGES 3200000
#define HIDDEN 256
#define EMBED 128
#define N_PAIRS 100000

typedef _Float16 half2v __attribute__((ext_vector_type(2)));
typedef _Float16 half4v __attribute__((ext_vector_type(4)));
typedef _Float16 half8v __attribute__((ext_vector_type(8)));
typedef float floatx2 __attribute__((ext_vector_type(2)));
typedef float floatx4 __attribute__((ext_vector_type(4)));
typedef unsigned int uintx2 __attribute__((ext_vector_type(2)));
typedef unsigned int uintx4 __attribute__((ext_vector_type(4)));

#define GLOBAL_AS __attribute__((address_space(1)))
#define LDS_AS __attribute__((address_space(3)))

// fp8 pre-scales: keep quantized values in e4m3 normal range
#define X8_SCALE 16.0f      // x ~ N(0,0.028) -> 0.45
#define X8_INV  (1.0f / 16.0f)
#define G8_SCALE 64.0f      // g ~ N(0,0.01)  -> 0.64
#define G8_INV  (1.0f / 64.0f)

static __device__ __forceinline__ void async_copy16(const void* g, void* lds) {
    __builtin_amdgcn_global_load_lds((const GLOBAL_AS unsigned int*)g,
                                     (LDS_AS unsigned int*)(void*)lds, 16, 0, 0);
}

// ---------------------------------------------------------------------------
// row_ptr from sorted rows (binary search, no atomics)
// ---------------------------------------------------------------------------
__global__ void build_rowptr_k(const int* __restrict__ rows, int* __restrict__ rp,
                               int n_nodes, int n_edges) {
    int n = blockIdx.x * blockDim.x + threadIdx.x;
    if (n > n_nodes) return;
    int lo = 0, hi = n_edges;
    while (lo < hi) {
        int mid = (lo + hi) >> 1;
        if (rows[mid] < n) lo = mid + 1; else hi = mid;
    }
    rp[n] = lo;
}

// ---------------------------------------------------------------------------
// x8[n][f] = fp8_e4m3((node_emb[n][f] + type_emb[type[n]][f]) * 16)
// ---------------------------------------------------------------------------
__global__ void build_x8_k(const float* __restrict__ node_emb,
                           const float* __restrict__ type_emb,
                           const int* __restrict__ ntype,
                           unsigned char* __restrict__ x8) {
    int idx = blockIdx.x * blockDim.x + threadIdx.x;
    int n  = idx >> 6;
    if (n >= N_NODES) return;
    int f4 = (idx & 63) * 4;
    int t = ntype[n];
    float4 a = *(const float4*)&node_emb[(size_t)n * HIDDEN + f4];
    float4 b = *(const float4*)&type_emb[(size_t)t * HIDDEN + f4];
    int w = __builtin_amdgcn_cvt_pk_fp8_f32((a.x + b.x) * X8_SCALE,
                                            (a.y + b.y) * X8_SCALE, 0, false);
    w     = __builtin_amdgcn_cvt_pk_fp8_f32((a.z + b.z) * X8_SCALE,
                                            (a.w + b.w) * X8_SCALE, w, true);
    *(int*)&x8[(size_t)n * HIDDEN + f4] = w;
}

// ---------------------------------------------------------------------------
// Wt[n][k] = fp16(W[k][n])  for K=256 weights (W1, W2)
// ---------------------------------------------------------------------------
__global__ void transpose_w_k(const float* __restrict__ W, _Float16* __restrict__ Wt,
                              int K, int N) {
    int idx = blockIdx.x * blockDim.x + threadIdx.x;   // idx = n*256 + k
    if (idx >= K * N) return;
    int k = idx & 255;
    int n = idx >> 8;
    Wt[idx] = (_Float16)W[(size_t)k * N + n];
}

// Wp1 [384,128] -> Wp1t [128][384] fp16
__global__ void transpose_wp1_k(const float* __restrict__ W, _Float16* __restrict__ Wt) {
    int k = threadIdx.x;   // 0..383
    int n = blockIdx.x;    // 0..127
    Wt[n * 384 + k] = (_Float16)W[(size_t)k * EMBED + n];
}

// ---------------------------------------------------------------------------
// spmm1: s1[n][0:256] fp16 = (1/16) * sum_e val[e] * fp8dec(x8[cols[e]][:])
// 16 lanes/node (4 nodes/wave), lane = 16 feats = 16B dwordx4 gather.
// 2.5x more resident nodes than 1 node/wave -> fewer L2 footprint sweeps.
// 8 edges in flight per node-group (4KB gather bytes / group-quad).
// ---------------------------------------------------------------------------
__global__ __launch_bounds__(256, 5) void spmm1_k(
        const int* __restrict__ rp, const int* __restrict__ cols,
        const float* __restrict__ vals,
        const unsigned char* __restrict__ x8,
        _Float16* __restrict__ s1) {
    int t = threadIdx.x;
    int wave = t >> 6, lane = t & 63;
    int g = lane >> 4, s = lane & 15;
    int n = blockIdx.x * 16 + wave * 4 + g;
    int e0 = rp[n], e1 = rp[n + 1];
    int fo = s * 16;
    const unsigned char* xbase = x8 + fo;
    float acc[16];
#pragma unroll
    for (int j = 0; j < 16; ++j) acc[j] = 0.f;

    for (int e = e0; e < e1; e += 8) {
        int c[8]; float v[8];
#pragma unroll
        for (int i = 0; i < 8; ++i) {
            int idx = e + i;
            bool ok = idx < e1;
            idx = ok ? idx : e;          // e < e1 guaranteed inside loop
            c[i] = cols[idx];
            v[i] = ok ? vals[idx] : 0.f;
        }
        uintx4 w[8];
#pragma unroll
        for (int i = 0; i < 8; ++i)
            w[i] = *(const uintx4*)&xbase[(size_t)c[i] * HIDDEN];
#pragma unroll
        for (int i = 0; i < 8; ++i) {
#pragma unroll
            for (int q = 0; q < 4; ++q) {
                int wq = (int)w[i][q];
                floatx2 lo = __builtin_amdgcn_cvt_pk_f32_fp8(wq, false);
                floatx2 hi = __builtin_amdgcn_cvt_pk_f32_fp8(wq, true);
                acc[q * 4 + 0] += v[i] * lo.x;
                acc[q * 4 + 1] += v[i] * lo.y;
                acc[q * 4 + 2] += v[i] * hi.x;
                acc[q * 4 + 3] += v[i] * hi.y;
            }
        }
    }
    half8v o0, o1;
#pragma unroll
    for (int j = 0; j < 8; ++j) {
        o0[j] = (_Float16)(acc[j] * X8_INV);
        o1[j] = (_Float16)(acc[8 + j] * X8_INV);
    }
    *(half8v*)&s1[(size_t)n * HIDDEN + fo]     = o0;
    *(half8v*)&s1[(size_t)n * HIDDEN + fo + 8] = o1;
}

// ---------------------------------------------------------------------------
// spmm2: z16[n][0:128] fp16 = (1/64) * sum_e val[e] * fp8dec(g8[cols[e]][:]) + b2
// 16 lanes/node (4 nodes/wave), lane = 8 feats = 8B dwordx2 gather.
// ---------------------------------------------------------------------------
__global__ __launch_bounds__(256, 6) void spmm2_k(
        const int* __restrict__ rp, const int* __restrict__ cols,
        const float* __restrict__ vals,
        const unsigned char* __restrict__ g8,
        const float* __restrict__ b2, _Float16* __restrict__ z16) {
    int t = threadIdx.x;
    int wave = t >> 6, lane = t & 63;
    int g = lane >> 4, s = lane & 15;
    int n = blockIdx.x * 16 + wave * 4 + g;
    int e0 = rp[n], e1 = rp[n + 1];
    int fo = s * 8;
    const unsigned char* gbase = g8 + fo;
    float acc[8];
#pragma unroll
    for (int j = 0; j < 8; ++j) acc[j] = 0.f;

    for (int e = e0; e < e1; e += 8) {
        int c[8]; float v[8];
#pragma unroll
        for (int i = 0; i < 8; ++i) {
            int idx = e + i;
            bool ok = idx < e1;
            idx = ok ? idx : e;
            c[i] = cols[idx];
            v[i] = ok ? vals[idx] : 0.f;
        }
        uintx2 w[8];
#pragma unroll
        for (int i = 0; i < 8; ++i)
            w[i] = *(const uintx2*)&gbase[(size_t)c[i] * EMBED];
#pragma unroll
        for (int i = 0; i < 8; ++i) {
#pragma unroll
            for (int q = 0; q < 2; ++q) {
                int wq = (int)w[i][q];
                floatx2 lo = __builtin_amdgcn_cvt_pk_f32_fp8(wq, false);
                floatx2 hi = __builtin_amdgcn_cvt_pk_f32_fp8(wq, true);
                acc[q * 4 + 0] += v[i] * lo.x;
                acc[q * 4 + 1] += v[i] * lo.y;
                acc[q * 4 + 2] += v[i] * hi.x;
                acc[q * 4 + 3] += v[i] * hi.y;
            }
        }
    }
    half8v o;
#pragma unroll
    for (int j = 0; j < 8; ++j)
        o[j] = (_Float16)(acc[j] * G8_INV + b2[fo + j]);
    *(half8v*)&z16[(size_t)n * EMBED + fo] = o;
}

// ---------------------------------------------------------------------------
// Wide fp16 MFMA GEMM for gcn1: h = relu(s1 @ W1t^T + b1)
// 128x256 tile (full N) -> A read exactly once. 512 thr = 8 waves (2x4),
// BK=32, 24KB LDS, global_load_lds width-16 staging.
// ---------------------------------------------------------------------------
__global__ __launch_bounds__(512) void gemm_wide_k(
        const _Float16* __restrict__ A, const _Float16* __restrict__ Bt,
        const float* __restrict__ bias, _Float16* __restrict__ C, int M) {
    const int K = 256;
    __shared__ _Float16 As[128 * 32];
    __shared__ _Float16 Bs[256 * 32];

    int t = threadIdx.x;
    int lane = t & 63;
    int wave = t >> 6;
    int quad = lane >> 4;
    int m16 = lane & 15;
    int wr = wave >> 2, wc = wave & 3;     // 2 x 4 wave grid
    int m0 = blockIdx.x * 128;

    int srow = t >> 2;                     // 0..127
    int skoff = (t & 3) * 8;

    floatx4 acc[4][4];
#pragma unroll
    for (int i = 0; i < 4; ++i)
#pragma unroll
        for (int j = 0; j < 4; ++j)
            acc[i][j] = (floatx4)0.f;

    for (int k0 = 0; k0 < K; k0 += 32) {
        int ra = m0 + srow; if (ra >= M) ra = M - 1;
        async_copy16(&A[(size_t)ra * K + k0 + skoff], &As[srow * 32 + skoff]);
        async_copy16(&Bt[(size_t)srow * K + k0 + skoff], &Bs[srow * 32 + skoff]);
        async_copy16(&Bt[(size_t)(srow + 128) * K + k0 + skoff], &Bs[(srow + 128) * 32 + skoff]);
        __syncthreads();

        half8v aF[4], bF[4];
#pragma unroll
        for (int i = 0; i < 4; ++i)
            aF[i] = *(const half8v*)&As[(wr * 64 + i * 16 + m16) * 32 + quad * 8];
#pragma unroll
        for (int j = 0; j < 4; ++j)
            bF[j] = *(const half8v*)&Bs[(wc * 64 + j * 16 + m16) * 32 + quad * 8];
#pragma unroll
        for (int i = 0; i < 4; ++i)
#pragma unroll
            for (int j = 0; j < 4; ++j)
                acc[i][j] = __builtin_amdgcn_mfma_f32_16x16x32_f16(aF[i], bF[j], acc[i][j], 0, 0, 0);
        __syncthreads();
    }

#pragma unroll
    for (int i = 0; i < 4; ++i) {
#pragma unroll
        for (int j = 0; j < 4; ++j) {
            int gr = m0 + wr * 64 + i * 16 + quad * 4;
            int gc = wc * 64 + j * 16 + m16;
            float bv = bias[gc];
#pragma unroll
            for (int r = 0; r < 4; ++r) {
                int row = gr + r;
                if (row < M) {
                    float v = acc[i][j][r] + bv;
                    v = v > 0.f ? v : 0.f;
                    C[(size_t)row * 256 + gc] = (_Float16)v;
                }
            }
        }
    }
}

// ---------------------------------------------------------------------------
// fp16 MFMA GEMM (gcn2): g8 = fp8(h @ W2t^T * 64), N = 128 (single tile col)
// 128x128 tile, BK=32, 256 thr
// ---------------------------------------------------------------------------
__global__ void gemm2_k(const _Float16* __restrict__ A,
                        const _Float16* __restrict__ Bt,
                        unsigned char* __restrict__ Cout,
                        int M, int N) {
    const int K = 256;
    __shared__ _Float16 As[128 * 32];
    __shared__ _Float16 Bs[128 * 32];

    int t = threadIdx.x;
    int lane = t & 63;
    int wave = t >> 6;
    int quad = lane >> 4;
    int m16 = lane & 15;
    int wr = wave >> 1, wc = wave & 1;
    int m0 = blockIdx.x * 128;
    int n0 = blockIdx.y * 128;

    int srow = t >> 2;
    int skoff = (t & 3) * 8;

    floatx4 acc[4][4];
#pragma unroll
    for (int i = 0; i < 4; ++i)
#pragma unroll
        for (int j = 0; j < 4; ++j)
            acc[i][j] = (floatx4)0.f;

    for (int k0 = 0; k0 < K; k0 += 32) {
        int ra0 = m0 + srow;       if (ra0 >= M) ra0 = M - 1;
        int ra1 = m0 + srow + 64;  if (ra1 >= M) ra1 = M - 1;
        async_copy16(&A[(size_t)ra0 * K + k0 + skoff], &As[srow * 32 + skoff]);
        async_copy16(&A[(size_t)ra1 * K + k0 + skoff], &As[(srow + 64) * 32 + skoff]);
        async_copy16(&Bt[(size_t)(n0 + srow) * K + k0 + skoff], &Bs[srow * 32 + skoff]);
        async_copy16(&Bt[(size_t)(n0 + srow + 64) * K + k0 + skoff], &Bs[(srow + 64) * 32 + skoff]);
        __syncthreads();

        half8v aF[4], bF[4];
#pragma unroll
        for (int i = 0; i < 4; ++i)
            aF[i] = *(const half8v*)&As[(wr * 64 + i * 16 + m16) * 32 + quad * 8];
#pragma unroll
        for (int j = 0; j < 4; ++j)
            bF[j] = *(const half8v*)&Bs[(wc * 64 + j * 16 + m16) * 32 + quad * 8];
#pragma unroll
        for (int i = 0; i < 4; ++i)
#pragma unroll
            for (int j = 0; j < 4; ++j)
                acc[i][j] = __builtin_amdgcn_mfma_f32_16x16x32_f16(aF[i], bF[j], acc[i][j], 0, 0, 0);
        __syncthreads();
    }

#pragma unroll
    for (int i = 0; i < 4; ++i) {
#pragma unroll
        for (int j = 0; j < 4; ++j) {
            int gr = m0 + wr * 64 + i * 16 + quad * 4;
            int gc = n0 + wc * 64 + j * 16 + m16;
#pragma unroll
            for (int r = 0; r < 4; ++r) {
                int row = gr + r;
                if (row < M) {
                    float sv = acc[i][j][r] * G8_SCALE;
                    int w = __builtin_amdgcn_cvt_pk_fp8_f32(sv, sv, 0, false);
                    Cout[(size_t)row * N + gc] = (unsigned char)(w & 0xFF);
                }
            }
        }
    }
}

// ---------------------------------------------------------------------------
// MFMA fp16 pair scorer: 128 pairs/block, N=128, K=384 in 3 regions of 128
// feat = [z[s] | z[d] | z[s]*z[d]]; out[p] = relu(feat@Wp1+bp1) . Wp2 + bp2
// ---------------------------------------------------------------------------
__global__ __launch_bounds__(256) void scorer_mfma_k(
        const _Float16* __restrict__ z16, const int* __restrict__ pairs,
        const _Float16* __restrict__ Wp1t, const float* __restrict__ bp1,
        const float* __restrict__ Wp2, const float* __restrict__ bp2,
        float* __restrict__ out, int P) {
    __shared__ _Float16 Fs[128][136];   // feat chunk [pair][k], +8 pad
    __shared__ _Float16 Ws[128][136];   // Wp1t chunk [n][k]
    __shared__ int sidx[128], didx[128];
    __shared__ float red[128][2];

    int t  = threadIdx.x;
    int p0 = blockIdx.x * 128;

    if (t < 128) {
        int p = p0 + t;
        if (p >= P) p = P - 1;
        sidx[t] = pairs[p];
        didx[t] = pairs[P + p];
    }
    __syncthreads();

    int lane = t & 63, wave = t >> 6;
    int quad = lane >> 4, m16 = lane & 15;
    int wr = wave >> 1, wc = wave & 1;

    floatx4 acc[4][4];
#pragma unroll
    for (int i = 0; i < 4; ++i)
#pragma unroll
        for (int j = 0; j < 4; ++j)
            acc[i][j] = (floatx4)0.f;

    int pr = t & 127;          // staging row (pair / n)
    int kh = (t >> 7) * 64;    // k-half offset 0 / 64

    for (int r = 0; r < 3; ++r) {
        // stage feat region
        {
            const _Float16* zs = &z16[(size_t)sidx[pr] * EMBED + kh];
            const _Float16* zd = &z16[(size_t)didx[pr] * EMBED + kh];
            half8v f[8];
            if (r == 0) {
#pragma unroll
                for (int i = 0; i < 8; ++i) f[i] = *(const half8v*)&zs[i * 8];
            } else if (r == 1) {
#pragma unroll
                for (int i = 0; i < 8; ++i) f[i] = *(const half8v*)&zd[i * 8];
            } else {
#pragma unroll
                for (int i = 0; i < 8; ++i) {
                    half8v a = *(const half8v*)&zs[i * 8];
                    half8v b = *(const half8v*)&zd[i * 8];
                    f[i] = a * b;
                }
            }
#pragma unroll
            for (int i = 0; i < 8; ++i)
                *(half8v*)&Fs[pr][kh + i * 8] = f[i];
        }
        // stage Wp1t region
        {
            const _Float16* wsrc = &Wp1t[(size_t)pr * 384 + r * 128 + kh];
#pragma unroll
            for (int i = 0; i < 8; ++i)
                *(half8v*)&Ws[pr][kh + i * 8] = *(const half8v*)&wsrc[i * 8];
        }
        __syncthreads();

#pragma unroll
        for (int k0 = 0; k0 < 128; k0 += 32) {
            half8v aF[4], bF[4];
#pragma unroll
            for (int i = 0; i < 4; ++i)
                aF[i] = *(const half8v*)&Fs[wr * 64 + i * 16 + m16][k0 + quad * 8];
#pragma unroll
            for (int j = 0; j < 4; ++j)
                bF[j] = *(const half8v*)&Ws[wc * 64 + j * 16 + m16][k0 + quad * 8];
#pragma unroll
            for (int i = 0; i < 4; ++i)
#pragma unroll
                for (int j = 0; j < 4; ++j)
                    acc[i][j] = __builtin_amdgcn_mfma_f32_16x16x32_f16(aF[i], bF[j], acc[i][j], 0, 0, 0);
        }
        __syncthreads();
    }

    // epilogue: relu(acc + bp1) . Wp2, shfl-reduce across the 16 col lanes
    float w2v[4], b1v[4];
#pragma unroll
    for (int j = 0; j < 4; ++j) {
        int col = wc * 64 + j * 16 + m16;
        w2v[j] = Wp2[col];
        b1v[j] = bp1[col];
    }
#pragma unroll
    for (int i = 0; i < 4; ++i) {
#pragma unroll
        for (int rr = 0; rr < 4; ++rr) {
            float partial = 0.f;
#pragma unroll
            for (int j = 0; j < 4; ++j) {
                float v = acc[i][j][rr] + b1v[j];
                v = v > 0.f ? v : 0.f;
                partial += v * w2v[j];
            }
#pragma unroll
            for (int off = 1; off < 16; off <<= 1)
                partial += __shfl_xor(partial, off, 64);
            if (m16 == 0)
                red[wr * 64 + i * 16 + quad * 4 + rr][wc] = partial;
        }
    }
    __syncthreads();
    if (t < 128) {
        int p = p0 + t;
        if (p < P) out[p] = red[t][0] + red[t][1] + bp2[0];
    }
}

// ---------------------------------------------------------------------------
// Launch
// ---------------------------------------------------------------------------
extern "C" void kernel_launch(void* const* d_in, const int* in_sizes, int n_in,
                              void* d_out, int out_size, void* d_ws, size_t ws_size,
                              hipStream_t stream) {
    const int*   node_type_ids = (const int*)d_in[0];
    const int*   rows          = (const int*)d_in[1];
    const int*   cols          = (const int*)d_in[2];
    const float* edge_vals     = (const float*)d_in[3];
    const int*   pairs         = (const int*)d_in[4];
    const float* node_emb      = (const float*)d_in[5];
    const float* type_emb      = (const float*)d_in[6];
    const float* W1            = (const float*)d_in[7];
    const float* b1            = (const float*)d_in[8];
    const float* W2            = (const float*)d_in[9];
    const float* b2            = (const float*)d_in[10];
    const float* Wp1           = (const float*)d_in[11];
    const float* bp1           = (const float*)d_in[12];
    const float* Wp2           = (const float*)d_in[13];
    const float* bp2           = (const float*)d_in[14];
    float* out = (float*)d_out;

    const size_t MB = 1ull << 20;
    char* ws = (char*)d_ws;
    int*      rp   = (int*)(ws);
    unsigned char* x8 = (unsigned char*)(ws + 4 * MB);   // [N][256] fp8 = 25.6MB
    _Float16* s1   = (_Float16*)(ws + 56 * MB);
    _Float16* h16  = (_Float16*)(ws + 108 * MB);
    unsigned char* g8 = (unsigned char*)(ws + 160 * MB); // [N][128] fp8 = 12.8MB
    _Float16* z16  = (_Float16*)(ws + 186 * MB);
    _Float16* W1t  = (_Float16*)(ws + 212 * MB);
    _Float16* W2t  = (_Float16*)(ws + 213 * MB);
    _Float16* Wp1t = (_Float16*)(ws + 214 * MB);

    // prep
    build_rowptr_k<<<(N_NODES + 256) / 256, 256, 0, stream>>>(rows, rp, N_NODES, N_EDGES);
    build_x8_k<<<(N_NODES * 64 + 255) / 256, 256, 0, stream>>>(node_emb, type_emb,
                                                               node_type_ids, x8);
    transpose_w_k<<<(HIDDEN * HIDDEN + 255) / 256, 256, 0, stream>>>(W1, W1t, HIDDEN, HIDDEN);
    transpose_w_k<<<(HIDDEN * EMBED + 255) / 256, 256, 0, stream>>>(W2, W2t, HIDDEN, EMBED);
    transpose_wp1_k<<<EMBED, 3 * EMBED, 0, stream>>>(Wp1, Wp1t);

    // s1 = spmm(x8)  (fp8 gather payload; 4 nodes/wave for L2 sweep reduction)
    spmm1_k<<<N_NODES / 16, 256, 0, stream>>>(rp, cols, edge_vals, x8, s1);

    // h = relu(s1 @ W1 + b1)  (128x256 tile, A read once)
    gemm_wide_k<<<(N_NODES + 127) / 128, 512, 0, stream>>>(s1, W1t, b1, h16, N_NODES);

    // g8 = fp8(h @ W2 * 64)   (z = spmm(g) + b2 by linearity)
    {
        dim3 grid((N_NODES + 127) / 128, EMBED / 128);
        gemm2_k<<<grid, 256, 0, stream>>>(h16, W2t, g8, N_NODES, EMBED);
    }

    // z16 = (1/64) * spmm(g8) + b2  (4 nodes/wave)
    spmm2_k<<<N_NODES / 16, 256, 0, stream>>>(rp, cols, edge_vals, g8, b2, z16);

    // scorer
    scorer_mfma_k<<<(N_PAIRS + 127) / 128, 256, 0, stream>>>(z16, pairs, Wp1t, bp1,
                                                             Wp2, bp2, out, N_PAIRS);
}

// Round 8
// 458.624 us; speedup vs baseline: 1.4276x; 1.0492x over previous
//
#include <hip/hip_runtime.h>
#include <hip/hip_bf16.h>

#define N_NODES 100000
#define N_TYPES 10
#define N_EDGES 3200000
#define HIDDEN 256
#define EMBED 128
#define N_PAIRS 100000

typedef _Float16 half2v __attribute__((ext_vector_type(2)));
typedef _Float16 half4v __attribute__((ext_vector_type(4)));
typedef _Float16 half8v __attribute__((ext_vector_type(8)));
typedef float floatx2 __attribute__((ext_vector_type(2)));
typedef float floatx4 __attribute__((ext_vector_type(4)));
typedef unsigned int uintx2 __attribute__((ext_vector_type(2)));

#define GLOBAL_AS __attribute__((address_space(1)))
#define LDS_AS __attribute__((address_space(3)))

// fp8 pre-scales: keep quantized values in e4m3 normal range.
// ONLY two quantization points (x8, g8) — error budget is fully spent
// (round 7: adding a third (h) gave 3.66e-4 > 3.64e-4 gate).
#define X8_SCALE 16.0f      // x ~ N(0,0.028) -> 0.45
#define X8_INV  (1.0f / 16.0f)
#define G8_SCALE 64.0f      // g ~ N(0,0.01)  -> 0.64
#define G8_INV  (1.0f / 64.0f)

static __device__ __forceinline__ void async_copy16(const void* g, void* lds) {
    __builtin_amdgcn_global_load_lds((const GLOBAL_AS unsigned int*)g,
                                     (LDS_AS unsigned int*)(void*)lds, 16, 0, 0);
}

// ---------------------------------------------------------------------------
// One segmented prep launch: rowptr | x8 quantize | W1t | W2t | Wp1t
// ---------------------------------------------------------------------------
#define SEG0 (N_NODES + 1)          // rowptr
#define SEG1 (N_NODES * 64)         // x8 (64 thr/node, 4 feats each)
#define SEG2 (HIDDEN * HIDDEN)      // W1t
#define SEG3 (HIDDEN * EMBED)       // W2t
#define SEG4 (3 * EMBED * EMBED)    // Wp1t
#define PREP_TOTAL (SEG0 + SEG1 + SEG2 + SEG3 + SEG4)

__global__ void prep_k(const int* __restrict__ rows, int* __restrict__ rp,
                       const float* __restrict__ node_emb,
                       const float* __restrict__ type_emb,
                       const int* __restrict__ ntype,
                       unsigned char* __restrict__ x8,
                       const float* __restrict__ W1, _Float16* __restrict__ W1t,
                       const float* __restrict__ W2, _Float16* __restrict__ W2t,
                       const float* __restrict__ Wp1, _Float16* __restrict__ Wp1t) {
    int gid = blockIdx.x * blockDim.x + threadIdx.x;
    if (gid < SEG0) {
        int n = gid;
        int lo = 0, hi = N_EDGES;
        while (lo < hi) {
            int mid = (lo + hi) >> 1;
            if (rows[mid] < n) lo = mid + 1; else hi = mid;
        }
        rp[n] = lo;
        return;
    }
    gid -= SEG0;
    if (gid < SEG1) {
        int n  = gid >> 6;
        int f4 = (gid & 63) * 4;
        int t = ntype[n];
        float4 a = *(const float4*)&node_emb[(size_t)n * HIDDEN + f4];
        float4 b = *(const float4*)&type_emb[(size_t)t * HIDDEN + f4];
        int w = __builtin_amdgcn_cvt_pk_fp8_f32((a.x + b.x) * X8_SCALE,
                                                (a.y + b.y) * X8_SCALE, 0, false);
        w     = __builtin_amdgcn_cvt_pk_fp8_f32((a.z + b.z) * X8_SCALE,
                                                (a.w + b.w) * X8_SCALE, w, true);
        *(int*)&x8[(size_t)n * HIDDEN + f4] = w;
        return;
    }
    gid -= SEG1;
    if (gid < SEG2) {                 // W1t[n*256+k] = W1[k*256+n]
        int k = gid & 255, n = gid >> 8;
        W1t[gid] = (_Float16)W1[(size_t)k * HIDDEN + n];
        return;
    }
    gid -= SEG2;
    if (gid < SEG3) {                 // W2t[n*256+k] = W2[k*128+n]
        int k = gid & 255, n = gid >> 8;
        W2t[gid] = (_Float16)W2[(size_t)k * EMBED + n];
        return;
    }
    gid -= SEG3;
    if (gid < SEG4) {                 // Wp1t[n*384+k] = Wp1[k*128+n]
        int n = gid / 384, k = gid - n * 384;
        Wp1t[n * 384 + k] = (_Float16)Wp1[(size_t)k * EMBED + n];
    }
}

// ---------------------------------------------------------------------------
// spmm1 (round-5 verified best): s1[n] = (1/16) * sum_e val[e]*fp8dec(x8[c_e])
// one wave/node, lane = 4 feats (4B dword gather, full 256B row/instr,
// WAVE-UNIFORM row index -> cols/vals in SGPRs); 16 edges in flight.
// ---------------------------------------------------------------------------
__global__ void spmm1_k(const int* __restrict__ rp, const int* __restrict__ cols,
                        const float* __restrict__ vals,
                        const unsigned char* __restrict__ x8,
                        _Float16* __restrict__ s1) {
    int wave = threadIdx.x >> 6, lane = threadIdx.x & 63;
    int n = blockIdx.x * 4 + wave;
    int e0 = rp[n], e1 = rp[n + 1];
    int fo = lane * 4;
    float a0 = 0.f, a1 = 0.f, a2 = 0.f, a3 = 0.f;
    int e = e0;
    for (; e + 16 <= e1; e += 16) {
        int c[16]; float v[16];
#pragma unroll
        for (int i = 0; i < 16; ++i) { c[i] = cols[e + i]; v[i] = vals[e + i]; }
        int w[16];
#pragma unroll
        for (int i = 0; i < 16; ++i)
            w[i] = *(const int*)&x8[(size_t)c[i] * HIDDEN + fo];
#pragma unroll
        for (int i = 0; i < 16; ++i) {
            floatx2 lo = __builtin_amdgcn_cvt_pk_f32_fp8(w[i], false);
            floatx2 hi = __builtin_amdgcn_cvt_pk_f32_fp8(w[i], true);
            a0 += v[i] * lo.x; a1 += v[i] * lo.y;
            a2 += v[i] * hi.x; a3 += v[i] * hi.y;
        }
    }
    for (; e + 4 <= e1; e += 4) {
        int c[4]; float v[4];
#pragma unroll
        for (int i = 0; i < 4; ++i) { c[i] = cols[e + i]; v[i] = vals[e + i]; }
        int w[4];
#pragma unroll
        for (int i = 0; i < 4; ++i)
            w[i] = *(const int*)&x8[(size_t)c[i] * HIDDEN + fo];
#pragma unroll
        for (int i = 0; i < 4; ++i) {
            floatx2 lo = __builtin_amdgcn_cvt_pk_f32_fp8(w[i], false);
            floatx2 hi = __builtin_amdgcn_cvt_pk_f32_fp8(w[i], true);
            a0 += v[i] * lo.x; a1 += v[i] * lo.y;
            a2 += v[i] * hi.x; a3 += v[i] * hi.y;
        }
    }
    for (; e < e1; ++e) {
        int c0 = cols[e]; float v0 = vals[e];
        int w0 = *(const int*)&x8[(size_t)c0 * HIDDEN + fo];
        floatx2 lo = __builtin_amdgcn_cvt_pk_f32_fp8(w0, false);
        floatx2 hi = __builtin_amdgcn_cvt_pk_f32_fp8(w0, true);
        a0 += v0 * lo.x; a1 += v0 * lo.y;
        a2 += v0 * hi.x; a3 += v0 * hi.y;
    }
    half4v o;
    o.x = (_Float16)(a0 * X8_INV); o.y = (_Float16)(a1 * X8_INV);
    o.z = (_Float16)(a2 * X8_INV); o.w = (_Float16)(a3 * X8_INV);
    *(half4v*)&s1[(size_t)n * HIDDEN + fo] = o;
}

// ---------------------------------------------------------------------------
// Fused gcn1+gcn2 (64-row tiles, h kept in LDS as FP16 -> bit-identical to
// the unfused rounds 5/6; no third quantization point):
//   phase 1: Hs = relu(s1[64 rows] @ W1t^T + b1)   (fp16 in LDS)
//   phase 2: g8 = fp8( Hs @ W2t^T * 64 )
// 512 thr = 8 waves. LDS: Hs 33.8KB + As 4KB + Bs 16KB = 53.8KB -> 2 blk/CU.
// ---------------------------------------------------------------------------
#define HS_PAD 264   // halfs per Hs row (256 + 8): phase-2 reads 2-way free

__global__ __launch_bounds__(512) void gcn12_fused_k(
        const _Float16* __restrict__ A, const _Float16* __restrict__ W1t,
        const float* __restrict__ b1, const _Float16* __restrict__ W2t,
        unsigned char* __restrict__ g8, int M) {
    const int K = 256;
    __shared__ _Float16 As[64 * 32];        // 4KB  (s1 chunk / unused ph2)
    __shared__ _Float16 Bs[256 * 32];       // 16KB (W1t chunk / W2t chunk)
    __shared__ _Float16 Hs[64 * HS_PAD];    // 33.8KB fp16 h tile

    int t = threadIdx.x;
    int lane = t & 63;
    int wave = t >> 6;
    int quad = lane >> 4;
    int m16 = lane & 15;
    int m0 = blockIdx.x * 64;

    int srow = t >> 2;            // 0..127
    int skoff = (t & 3) * 8;

    // ---------------- phase 1: 64x256 = s1 @ W1 ----------------
    {
        int wr = wave >> 2, wc = wave & 3;       // 2 x 4 wave grid
        floatx4 acc[2][4];
#pragma unroll
        for (int i = 0; i < 2; ++i)
#pragma unroll
            for (int j = 0; j < 4; ++j)
                acc[i][j] = (floatx4)0.f;

        for (int k0 = 0; k0 < K; k0 += 32) {
            if (t < 256) {                       // As: 64 rows x 32 k
                int ra = m0 + srow; if (ra >= M) ra = M - 1;
                async_copy16(&A[(size_t)ra * K + k0 + skoff], &As[srow * 32 + skoff]);
            }
            // Bs: 256 rows x 32 k (2 chunks/thread)
            async_copy16(&W1t[(size_t)srow * K + k0 + skoff], &Bs[srow * 32 + skoff]);
            async_copy16(&W1t[(size_t)(srow + 128) * K + k0 + skoff],
                         &Bs[(srow + 128) * 32 + skoff]);
            __syncthreads();

            half8v aF[2], bF[4];
#pragma unroll
            for (int i = 0; i < 2; ++i)
                aF[i] = *(const half8v*)&As[(wr * 32 + i * 16 + m16) * 32 + quad * 8];
#pragma unroll
            for (int j = 0; j < 4; ++j)
                bF[j] = *(const half8v*)&Bs[(wc * 64 + j * 16 + m16) * 32 + quad * 8];
#pragma unroll
            for (int i = 0; i < 2; ++i)
#pragma unroll
                for (int j = 0; j < 4; ++j)
                    acc[i][j] = __builtin_amdgcn_mfma_f32_16x16x32_f16(aF[i], bF[j], acc[i][j], 0, 0, 0);
            __syncthreads();
        }

        // epilogue -> Hs (fp16, relu) — exact same values as unfused h16
#pragma unroll
        for (int i = 0; i < 2; ++i) {
#pragma unroll
            for (int j = 0; j < 4; ++j) {
                int lr = wr * 32 + i * 16 + quad * 4;    // local row 0..63
                int gc = wc * 64 + j * 16 + m16;         // h feature 0..255
                float bv = b1[gc];
#pragma unroll
                for (int r = 0; r < 4; ++r) {
                    float v = acc[i][j][r] + bv;
                    v = v > 0.f ? v : 0.f;
                    Hs[(lr + r) * HS_PAD + gc] = (_Float16)v;
                }
            }
        }
    }
    __syncthreads();

    // ---------------- phase 2: 64x128 = Hs @ W2 ----------------
    {
        int wr = wave >> 2, wc = wave & 3;       // 2 row-blk(32) x 4 col-blk(32)
        floatx4 acc2[2][2];
#pragma unroll
        for (int i = 0; i < 2; ++i)
#pragma unroll
            for (int j = 0; j < 2; ++j)
                acc2[i][j] = (floatx4)0.f;

        for (int k0 = 0; k0 < K; k0 += 32) {
            // W2t chunk: 128 rows x 32 k into Bs (1 chunk/thread)
            async_copy16(&W2t[(size_t)srow * K + k0 + skoff], &Bs[srow * 32 + skoff]);
            __syncthreads();

            half8v aF[2], bF[2];
#pragma unroll
            for (int i = 0; i < 2; ++i)
                aF[i] = *(const half8v*)&Hs[(wr * 32 + i * 16 + m16) * HS_PAD + k0 + quad * 8];
#pragma unroll
            for (int j = 0; j < 2; ++j)
                bF[j] = *(const half8v*)&Bs[(wc * 32 + j * 16 + m16) * 32 + quad * 8];
#pragma unroll
            for (int i = 0; i < 2; ++i)
#pragma unroll
                for (int j = 0; j < 2; ++j)
                    acc2[i][j] = __builtin_amdgcn_mfma_f32_16x16x32_f16(aF[i], bF[j], acc2[i][j], 0, 0, 0);
            __syncthreads();
        }

        // epilogue: g8 = fp8(h@W2 * 64)
#pragma unroll
        for (int i = 0; i < 2; ++i) {
#pragma unroll
            for (int j = 0; j < 2; ++j) {
                int gr = m0 + wr * 32 + i * 16 + quad * 4;
                int gc = wc * 32 + j * 16 + m16;
#pragma unroll
                for (int r = 0; r < 4; ++r) {
                    int row = gr + r;
                    if (row < M) {
                        float sv = acc2[i][j][r] * G8_SCALE;
                        int w = __builtin_amdgcn_cvt_pk_fp8_f32(sv, sv, 0, false);
                        g8[(size_t)row * EMBED + gc] = (unsigned char)(w & 0xFF);
                    }
                }
            }
        }
    }
}

// ---------------------------------------------------------------------------
// spmm2: z16[n][0:128] = (1/64) * sum_e val[e]*fp8dec(g8[c_e]) + b2
// 16 lanes/node (4 nodes/wave), lane = 8 feats = 8B dwordx2 gather (round-6).
// ---------------------------------------------------------------------------
__global__ __launch_bounds__(256, 6) void spmm2_k(
        const int* __restrict__ rp, const int* __restrict__ cols,
        const float* __restrict__ vals,
        const unsigned char* __restrict__ g8,
        const float* __restrict__ b2, _Float16* __restrict__ z16) {
    int t = threadIdx.x;
    int wave = t >> 6, lane = t & 63;
    int g = lane >> 4, s = lane & 15;
    int n = blockIdx.x * 16 + wave * 4 + g;
    int e0 = rp[n], e1 = rp[n + 1];
    int fo = s * 8;
    const unsigned char* gbase = g8 + fo;
    float acc[8];
#pragma unroll
    for (int j = 0; j < 8; ++j) acc[j] = 0.f;

    for (int e = e0; e < e1; e += 8) {
        int c[8]; float v[8];
#pragma unroll
        for (int i = 0; i < 8; ++i) {
            int idx = e + i;
            bool ok = idx < e1;
            idx = ok ? idx : e;
            c[i] = cols[idx];
            v[i] = ok ? vals[idx] : 0.f;
        }
        uintx2 w[8];
#pragma unroll
        for (int i = 0; i < 8; ++i)
            w[i] = *(const uintx2*)&gbase[(size_t)c[i] * EMBED];
#pragma unroll
        for (int i = 0; i < 8; ++i) {
#pragma unroll
            for (int q = 0; q < 2; ++q) {
                int wq = (int)w[i][q];
                floatx2 lo = __builtin_amdgcn_cvt_pk_f32_fp8(wq, false);
                floatx2 hi = __builtin_amdgcn_cvt_pk_f32_fp8(wq, true);
                acc[q * 4 + 0] += v[i] * lo.x;
                acc[q * 4 + 1] += v[i] * lo.y;
                acc[q * 4 + 2] += v[i] * hi.x;
                acc[q * 4 + 3] += v[i] * hi.y;
            }
        }
    }
    half8v o;
#pragma unroll
    for (int j = 0; j < 8; ++j)
        o[j] = (_Float16)(acc[j] * G8_INV + b2[fo + j]);
    *(half8v*)&z16[(size_t)n * EMBED + fo] = o;
}

// ---------------------------------------------------------------------------
// MFMA fp16 pair scorer: 128 pairs/block, N=128, K=384 in 3 regions of 128
// ---------------------------------------------------------------------------
__global__ __launch_bounds__(256) void scorer_mfma_k(
        const _Float16* __restrict__ z16, const int* __restrict__ pairs,
        const _Float16* __restrict__ Wp1t, const float* __restrict__ bp1,
        const float* __restrict__ Wp2, const float* __restrict__ bp2,
        float* __restrict__ out, int P) {
    __shared__ _Float16 Fs[128][136];
    __shared__ _Float16 Ws[128][136];
    __shared__ int sidx[128], didx[128];
    __shared__ float red[128][2];

    int t  = threadIdx.x;
    int p0 = blockIdx.x * 128;

    if (t < 128) {
        int p = p0 + t;
        if (p >= P) p = P - 1;
        sidx[t] = pairs[p];
        didx[t] = pairs[P + p];
    }
    __syncthreads();

    int lane = t & 63, wave = t >> 6;
    int quad = lane >> 4, m16 = lane & 15;
    int wr = wave >> 1, wc = wave & 1;

    floatx4 acc[4][4];
#pragma unroll
    for (int i = 0; i < 4; ++i)
#pragma unroll
        for (int j = 0; j < 4; ++j)
            acc[i][j] = (floatx4)0.f;

    int pr = t & 127;
    int kh = (t >> 7) * 64;

    for (int r = 0; r < 3; ++r) {
        {
            const _Float16* zs = &z16[(size_t)sidx[pr] * EMBED + kh];
            const _Float16* zd = &z16[(size_t)didx[pr] * EMBED + kh];
            half8v f[8];
            if (r == 0) {
#pragma unroll
                for (int i = 0; i < 8; ++i) f[i] = *(const half8v*)&zs[i * 8];
            } else if (r == 1) {
#pragma unroll
                for (int i = 0; i < 8; ++i) f[i] = *(const half8v*)&zd[i * 8];
            } else {
#pragma unroll
                for (int i = 0; i < 8; ++i) {
                    half8v a = *(const half8v*)&zs[i * 8];
                    half8v b = *(const half8v*)&zd[i * 8];
                    f[i] = a * b;
                }
            }
#pragma unroll
            for (int i = 0; i < 8; ++i)
                *(half8v*)&Fs[pr][kh + i * 8] = f[i];
        }
        {
            const _Float16* wsrc = &Wp1t[(size_t)pr * 384 + r * 128 + kh];
#pragma unroll
            for (int i = 0; i < 8; ++i)
                *(half8v*)&Ws[pr][kh + i * 8] = *(const half8v*)&wsrc[i * 8];
        }
        __syncthreads();

#pragma unroll
        for (int k0 = 0; k0 < 128; k0 += 32) {
            half8v aF[4], bF[4];
#pragma unroll
            for (int i = 0; i < 4; ++i)
                aF[i] = *(const half8v*)&Fs[wr * 64 + i * 16 + m16][k0 + quad * 8];
#pragma unroll
            for (int j = 0; j < 4; ++j)
                bF[j] = *(const half8v*)&Ws[wc * 64 + j * 16 + m16][k0 + quad * 8];
#pragma unroll
            for (int i = 0; i < 4; ++i)
#pragma unroll
                for (int j = 0; j < 4; ++j)
                    acc[i][j] = __builtin_amdgcn_mfma_f32_16x16x32_f16(aF[i], bF[j], acc[i][j], 0, 0, 0);
        }
        __syncthreads();
    }

    float w2v[4], b1v[4];
#pragma unroll
    for (int j = 0; j < 4; ++j) {
        int col = wc * 64 + j * 16 + m16;
        w2v[j] = Wp2[col];
        b1v[j] = bp1[col];
    }
#pragma unroll
    for (int i = 0; i < 4; ++i) {
#pragma unroll
        for (int rr = 0; rr < 4; ++rr) {
            float partial = 0.f;
#pragma unroll
            for (int j = 0; j < 4; ++j) {
                float v = acc[i][j][rr] + b1v[j];
                v = v > 0.f ? v : 0.f;
                partial += v * w2v[j];
            }
#pragma unroll
            for (int off = 1; off < 16; off <<= 1)
                partial += __shfl_xor(partial, off, 64);
            if (m16 == 0)
                red[wr * 64 + i * 16 + quad * 4 + rr][wc] = partial;
        }
    }
    __syncthreads();
    if (t < 128) {
        int p = p0 + t;
        if (p < P) out[p] = red[t][0] + red[t][1] + bp2[0];
    }
}

// ---------------------------------------------------------------------------
// Launch
// ---------------------------------------------------------------------------
extern "C" void kernel_launch(void* const* d_in, const int* in_sizes, int n_in,
                              void* d_out, int out_size, void* d_ws, size_t ws_size,
                              hipStream_t stream) {
    const int*   node_type_ids = (const int*)d_in[0];
    const int*   rows          = (const int*)d_in[1];
    const int*   cols          = (const int*)d_in[2];
    const float* edge_vals     = (const float*)d_in[3];
    const int*   pairs         = (const int*)d_in[4];
    const float* node_emb      = (const float*)d_in[5];
    const float* type_emb      = (const float*)d_in[6];
    const float* W1            = (const float*)d_in[7];
    const float* b1            = (const float*)d_in[8];
    const float* W2            = (const float*)d_in[9];
    const float* b2            = (const float*)d_in[10];
    const float* Wp1           = (const float*)d_in[11];
    const float* bp1           = (const float*)d_in[12];
    const float* Wp2           = (const float*)d_in[13];
    const float* bp2           = (const float*)d_in[14];
    float* out = (float*)d_out;

    const size_t MB = 1ull << 20;
    char* ws = (char*)d_ws;
    int*      rp   = (int*)(ws);
    unsigned char* x8 = (unsigned char*)(ws + 4 * MB);   // [N][256] fp8 = 25.6MB
    _Float16* s1   = (_Float16*)(ws + 56 * MB);
    unsigned char* g8 = (unsigned char*)(ws + 160 * MB); // [N][128] fp8 = 12.8MB
    _Float16* z16  = (_Float16*)(ws + 186 * MB);
    _Float16* W1t  = (_Float16*)(ws + 212 * MB);
    _Float16* W2t  = (_Float16*)(ws + 213 * MB);
    _Float16* Wp1t = (_Float16*)(ws + 214 * MB);

    // prep (one launch: rowptr + x8 + W1t + W2t + Wp1t)
    prep_k<<<(PREP_TOTAL + 255) / 256, 256, 0, stream>>>(
        rows, rp, node_emb, type_emb, node_type_ids, x8,
        W1, W1t, W2, W2t, Wp1, Wp1t);

    // s1 = spmm(x8)
    spmm1_k<<<N_NODES / 4, 256, 0, stream>>>(rp, cols, edge_vals, x8, s1);

    // g8 = fp8( relu(s1@W1+b1) @ W2 * 64 )   (h stays fp16 in LDS, fused)
    gcn12_fused_k<<<(N_NODES + 63) / 64, 512, 0, stream>>>(
        s1, W1t, b1, W2t, g8, N_NODES);

    // z16 = (1/64) * spmm(g8) + b2
    spmm2_k<<<N_NODES / 16, 256, 0, stream>>>(rp, cols, edge_vals, g8, b2, z16);

    // scorer
    scorer_mfma_k<<<(N_PAIRS + 127) / 128, 256, 0, stream>>>(z16, pairs, Wp1t, bp1,
                                                             Wp2, bp2, out, N_PAIRS);
}